// Round 2
// baseline (1336.147 us; speedup 1.0000x reference)
//
#include <hip/hip_runtime.h>

#define NN 50000
#define EE 800000      // 750000 random + 50000 self-loops
#define IND 512
#define HD 64
#define NB_SCAN 49     // ceil(NN/1024)

__device__ __forceinline__ float lrelu(float x, float s){ return x > 0.f ? x : s*x; }

// ---------------- CSR build (by dst) ----------------
__global__ void k_deg(const int* __restrict__ dst, int* __restrict__ deg){
  int e = blockIdx.x*256 + threadIdx.x;
  if(e < EE) atomicAdd(&deg[dst[e]], 1);
}

__global__ void k_scan1(const int* __restrict__ deg, int* __restrict__ psum){
  __shared__ int sh[256];
  int base = blockIdx.x*1024 + threadIdx.x*4;
  int s = 0;
  #pragma unroll
  for(int j=0;j<4;j++){ int i=base+j; if(i<NN) s += deg[i]; }
  sh[threadIdx.x]=s; __syncthreads();
  for(int st=128; st>0; st>>=1){ if(threadIdx.x<st) sh[threadIdx.x]+=sh[threadIdx.x+st]; __syncthreads(); }
  if(threadIdx.x==0) psum[blockIdx.x]=sh[0];
}

__global__ void k_scan2(int* __restrict__ psum, int nb){
  if(threadIdx.x==0){ int acc=0; for(int i=0;i<nb;i++){ int v=psum[i]; psum[i]=acc; acc+=v; } psum[nb]=acc; }
}

__global__ void k_scan3(const int* __restrict__ deg, const int* __restrict__ psum, int* __restrict__ rowp){
  __shared__ int sh[256];
  int t = threadIdx.x;
  int base = blockIdx.x*1024 + t*4;
  int v[4]; int s=0;
  #pragma unroll
  for(int j=0;j<4;j++){ int i=base+j; v[j] = (i<NN)?deg[i]:0; s+=v[j]; }
  sh[t]=s; __syncthreads();
  for(int st=1; st<256; st<<=1){
    int add = (t>=st)? sh[t-st] : 0;
    __syncthreads();
    sh[t] += add;
    __syncthreads();
  }
  int excl = sh[t]-s + psum[blockIdx.x];
  #pragma unroll
  for(int j=0;j<4;j++){ int i=base+j; if(i<NN){ rowp[i]=excl; excl+=v[j]; } }
  if(blockIdx.x==0 && t==0) rowp[NN] = psum[NB_SCAN];
}

__global__ void k_fill(const int* __restrict__ src, const int* __restrict__ dst,
                       const int* __restrict__ rowp, int* __restrict__ cnt, int* __restrict__ csrc){
  int e = blockIdx.x*256 + threadIdx.x;
  if(e < EE){
    int d = dst[e];
    int p = atomicAdd(&cnt[d], 1);
    csrc[rowp[d] + p] = src[e];
  }
}

// ---------------- shared GEMM tile machinery (64x64 C-tile, 256 thr, 4x4/thr) ----------------
__device__ __forceinline__ void load_A_tile(const float* __restrict__ A, int row0, int lda, int kcol0, float* As){
  int t = threadIdx.x;
  int lr = t>>2;             // row 0..63
  int lc = (t&3)*16;         // k base 0/16/32/48
  float4 a[4];
  int row = row0 + lr;
  if(row < NN){
    const float* ap = A + (size_t)row*lda + kcol0 + lc;
    a[0]=*(const float4*)ap; a[1]=*(const float4*)(ap+4); a[2]=*(const float4*)(ap+8); a[3]=*(const float4*)(ap+12);
  } else {
    a[0]=a[1]=a[2]=a[3]=make_float4(0.f,0.f,0.f,0.f);
  }
  const float* av = (const float*)a;
  #pragma unroll
  for(int q=0;q<16;q++) As[(lc+q)*68 + lr] = av[q];
}

__device__ __forceinline__ void load_B_tile(const float* __restrict__ B, int krow0, float* Bs){
  int t = threadIdx.x;
  int bk = t>>2; int lc = (t&3)*16;
  const float* bp = B + (size_t)(krow0+bk)*64 + lc;
  *(float4*)(Bs + bk*64 + lc)      = *(const float4*)bp;
  *(float4*)(Bs + bk*64 + lc + 4)  = *(const float4*)(bp+4);
  *(float4*)(Bs + bk*64 + lc + 8)  = *(const float4*)(bp+8);
  *(float4*)(Bs + bk*64 + lc + 12) = *(const float4*)(bp+12);
}

__device__ __forceinline__ void tile64_compute(const float* __restrict__ As, const float* __restrict__ Bs,
                                               float acc[4][4], int ty, int tx){
  #pragma unroll
  for(int kk=0; kk<64; kk++){
    float4 a = *(const float4*)(As + kk*68 + ty*4);
    float4 b = *(const float4*)(Bs + kk*64 + tx*4);
    acc[0][0]+=a.x*b.x; acc[0][1]+=a.x*b.y; acc[0][2]+=a.x*b.z; acc[0][3]+=a.x*b.w;
    acc[1][0]+=a.y*b.x; acc[1][1]+=a.y*b.y; acc[1][2]+=a.y*b.z; acc[1][3]+=a.y*b.w;
    acc[2][0]+=a.z*b.x; acc[2][1]+=a.z*b.y; acc[2][2]+=a.z*b.z; acc[2][3]+=a.z*b.w;
    acc[3][0]+=a.w*b.x; acc[3][1]+=a.w*b.y; acc[3][2]+=a.w*b.z; acc[3][3]+=a.w*b.w;
  }
}

// proj_feat = ft @ Wp   [NN,512]@[512,64]
__global__ __launch_bounds__(256) void k_gemm_proj(const float* __restrict__ A, const float* __restrict__ B, float* __restrict__ C){
  __shared__ float As[64*68];
  __shared__ float Bs[64*64];
  int row0 = blockIdx.x*64;
  int ty = threadIdx.x>>4, tx = threadIdx.x&15;
  float acc[4][4] = {};
  for(int kt=0; kt<IND; kt+=64){
    __syncthreads();
    load_A_tile(A, row0, IND, kt, As);
    load_B_tile(B, kt, Bs);
    __syncthreads();
    tile64_compute(As, Bs, acc, ty, tx);
  }
  #pragma unroll
  for(int i=0;i<4;i++){
    int row = row0 + ty*4 + i;
    if(row < NN) *(float4*)(C + (size_t)row*64 + tx*4) = make_float4(acc[i][0],acc[i][1],acc[i][2],acc[i][3]);
  }
}

// node matmuls merged: proj_z = cur@We AND pooled = cur@Wg  (A-tile loaded once)
__global__ __launch_bounds__(256) void k_nodemm2(const float* __restrict__ cur, const float* __restrict__ We,
                                                 const float* __restrict__ Wg,
                                                 float* __restrict__ projz, float* __restrict__ pooled){
  __shared__ float As[64*68];
  __shared__ float Bs[64*64];
  int row0 = blockIdx.x*64;
  int ty = threadIdx.x>>4, tx = threadIdx.x&15;
  load_A_tile(cur, row0, 64, 0, As);
  load_B_tile(We, 0, Bs);
  __syncthreads();
  float acc[4][4] = {};
  tile64_compute(As, Bs, acc, ty, tx);
  #pragma unroll
  for(int i=0;i<4;i++){
    int row = row0 + ty*4 + i;
    if(row < NN) *(float4*)(projz + (size_t)row*64 + tx*4) = make_float4(acc[i][0],acc[i][1],acc[i][2],acc[i][3]);
  }
  __syncthreads();                       // everyone done reading Bs
  load_B_tile(Wg, 0, Bs);
  __syncthreads();
  float acc2[4][4] = {};
  tile64_compute(As, Bs, acc2, ty, tx);
  #pragma unroll
  for(int i=0;i<4;i++){
    int row = row0 + ty*4 + i;
    if(row < NN) *(float4*)(pooled + (size_t)row*64 + tx*4) = make_float4(acc2[i][0],acc2[i][1],acc2[i][2],acc2[i][3]);
  }
}

// el/er per node per head (wave per node, butterfly reduce)
__global__ __launch_bounds__(256) void k_eler(const float* __restrict__ projz, const float* __restrict__ al,
                                              const float* __restrict__ ar, float* __restrict__ el, float* __restrict__ er){
  int wid = threadIdx.x>>6, lane = threadIdx.x&63;
  int n = blockIdx.x*4 + wid;
  if(n >= NN) return;
  float z = projz[(size_t)n*64 + lane];
  #pragma unroll
  for(int h=0; h<4; h++){
    float pl = z*al[h*64+lane];
    float pr = z*ar[h*64+lane];
    #pragma unroll
    for(int st=32; st; st>>=1){ pl += __shfl_xor(pl, st, 64); pr += __shfl_xor(pr, st, 64); }
    if(lane==0){ el[(size_t)n*4+h]=pl; er[(size_t)n*4+h]=pr; }
  }
}

// per-node edge kernel: softmax over edges + per-head weighted sum of CUR (pre-Wv) + GaAN gate
// writes aggcg[d, h*64+lane] = g_h * (sum_e alpha_e * cur[src_e])[lane]
__global__ __launch_bounds__(256) void k_edge(const int* __restrict__ rowp, const int* __restrict__ csrc,
    const float* __restrict__ el, const float* __restrict__ er, const float* __restrict__ cur,
    const float* __restrict__ pooled,
    const float* __restrict__ Wg, const float* __restrict__ bg, float* __restrict__ aggcg)
{
  int wid = threadIdx.x>>6, lane = threadIdx.x&63;
  int d = blockIdx.x*4 + wid;
  if(d >= NN) return;
  int e0 = rowp[d], e1 = rowp[d+1];
  float4 erd = *(const float4*)(er + (size_t)d*4);
  // pass 1: per-head max logit (lanes over edges)
  float m0=-1e30f, m1=-1e30f, m2=-1e30f, m3=-1e30f;
  for(int e=e0+lane; e<e1; e+=64){
    int s = csrc[e];
    float4 ev = *(const float4*)(el + (size_t)s*4);
    m0 = fmaxf(m0, lrelu(ev.x+erd.x, 0.2f));
    m1 = fmaxf(m1, lrelu(ev.y+erd.y, 0.2f));
    m2 = fmaxf(m2, lrelu(ev.z+erd.z, 0.2f));
    m3 = fmaxf(m3, lrelu(ev.w+erd.w, 0.2f));
  }
  #pragma unroll
  for(int st=32; st; st>>=1){
    m0=fmaxf(m0,__shfl_xor(m0,st,64)); m1=fmaxf(m1,__shfl_xor(m1,st,64));
    m2=fmaxf(m2,__shfl_xor(m2,st,64)); m3=fmaxf(m3,__shfl_xor(m3,st,64));
  }
  // pass 2: sequential edges, lanes over 64 dims; one cur load feeds 4 heads + mean
  float n0=0,n1=0,n2=0,n3=0, den0=0,den1=0,den2=0,den3=0, mn=0, mxp=-1e30f;
  for(int e=e0; e<e1; ++e){
    int s = csrc[e];                                   // wave-uniform
    float4 ev = *(const float4*)(el + (size_t)s*4);    // wave-uniform
    float x0 = __expf(lrelu(ev.x+erd.x,0.2f)-m0);
    float x1 = __expf(lrelu(ev.y+erd.y,0.2f)-m1);
    float x2 = __expf(lrelu(ev.z+erd.z,0.2f)-m2);
    float x3 = __expf(lrelu(ev.w+erd.w,0.2f)-m3);
    den0+=x0; den1+=x1; den2+=x2; den3+=x3;
    float cv = cur[(size_t)s*64 + lane];
    n0 += x0*cv; n1 += x1*cv; n2 += x2*cv; n3 += x3*cv;
    mn += cv;
    mxp = fmaxf(mxp, pooled[(size_t)s*64 + lane]);
  }
  // GaAN gate
  float cd  = cur[(size_t)d*64 + lane];
  float mnn = mn / (float)(e1-e0);
  float4 w0 = *(const float4*)(Wg + lane*4);
  float4 w1 = *(const float4*)(Wg + (64+lane)*4);
  float4 w2 = *(const float4*)(Wg + (128+lane)*4);
  float g0 = cd*w0.x + mxp*w1.x + mnn*w2.x;
  float g1 = cd*w0.y + mxp*w1.y + mnn*w2.y;
  float g2 = cd*w0.z + mxp*w1.z + mnn*w2.z;
  float g3 = cd*w0.w + mxp*w1.w + mnn*w2.w;
  #pragma unroll
  for(int st=32; st; st>>=1){
    g0+=__shfl_xor(g0,st,64); g1+=__shfl_xor(g1,st,64);
    g2+=__shfl_xor(g2,st,64); g3+=__shfl_xor(g3,st,64);
  }
  g0 = 1.f/(1.f+__expf(-(g0+bg[0])));
  g1 = 1.f/(1.f+__expf(-(g1+bg[1])));
  g2 = 1.f/(1.f+__expf(-(g2+bg[2])));
  g3 = 1.f/(1.f+__expf(-(g3+bg[3])));
  float* od = aggcg + (size_t)d*256;
  od[lane]       = g0 * n0/den0;
  od[64 + lane]  = g1 * n1/den1;
  od[128 + lane] = g2 * n2/den2;
  od[192 + lane] = g3 * n3/den3;
}

// layer0 post: cur1 = lrelu(0.25 * aggcg[N,256] @ WvStack[256,64])
__global__ __launch_bounds__(256) void k_post0(const float* __restrict__ A, const float* __restrict__ B, float* __restrict__ C){
  __shared__ float As[64*68];
  __shared__ float Bs[64*64];
  int row0 = blockIdx.x*64;
  int ty = threadIdx.x>>4, tx = threadIdx.x&15;
  float acc[4][4] = {};
  for(int kt=0; kt<256; kt+=64){
    __syncthreads();
    load_A_tile(A, row0, 256, kt, As);
    load_B_tile(B, kt, Bs);
    __syncthreads();
    tile64_compute(As, Bs, acc, ty, tx);
  }
  #pragma unroll
  for(int i=0;i<4;i++){
    int row = row0 + ty*4 + i;
    if(row < NN) *(float4*)(C + (size_t)row*64 + tx*4) =
      make_float4(lrelu(0.25f*acc[i][0],0.01f), lrelu(0.25f*acc[i][1],0.01f),
                  lrelu(0.25f*acc[i][2],0.01f), lrelu(0.25f*acc[i][3],0.01f));
  }
}

// layer1 post: cur2[:, h*64:(h+1)*64] = lrelu(aggcg[:, h*64:]@Wv1[h])  (block-diagonal)
__global__ __launch_bounds__(256) void k_post1(const float* __restrict__ aggcg, const float* __restrict__ Wv1, float* __restrict__ cur2){
  __shared__ float As[64*68];
  __shared__ float Bs[64*64];
  int h = blockIdx.y;
  const float* A = aggcg + h*64;          // lda 256
  const float* B = Wv1 + (size_t)h*4096;  // [64,64]
  float* C = cur2 + h*64;                 // ldc 256
  int row0 = blockIdx.x*64;
  int ty = threadIdx.x>>4, tx = threadIdx.x&15;
  load_A_tile(A, row0, 256, 0, As);
  load_B_tile(B, 0, Bs);
  __syncthreads();
  float acc[4][4] = {};
  tile64_compute(As, Bs, acc, ty, tx);
  #pragma unroll
  for(int i=0;i<4;i++){
    int row = row0 + ty*4 + i;
    if(row < NN) *(float4*)(C + (size_t)row*256 + tx*4) =
      make_float4(lrelu(acc[i][0],0.01f), lrelu(acc[i][1],0.01f),
                  lrelu(acc[i][2],0.01f), lrelu(acc[i][3],0.01f));
  }
}

// out = concat(proj_feat, cur2) @ Wtran + btran   (K=320)
__global__ __launch_bounds__(256) void k_final(const float* __restrict__ pf, const float* __restrict__ cur2,
                                               const float* __restrict__ Wt, const float* __restrict__ bt,
                                               float* __restrict__ C){
  __shared__ float As[64*68];
  __shared__ float Bs[64*64];
  int row0 = blockIdx.x*64;
  int ty = threadIdx.x>>4, tx = threadIdx.x&15;
  float acc[4][4] = {};
  for(int kt=0; kt<320; kt+=64){
    __syncthreads();
    if(kt==0) load_A_tile(pf, row0, 64, 0, As);
    else      load_A_tile(cur2, row0, 256, kt-64, As);
    load_B_tile(Wt, kt, Bs);
    __syncthreads();
    tile64_compute(As, Bs, acc, ty, tx);
  }
  float4 bias = *(const float4*)(bt + tx*4);
  #pragma unroll
  for(int i=0;i<4;i++){
    int row = row0 + ty*4 + i;
    if(row < NN){
      *(float4*)(C + (size_t)row*64 + tx*4) =
        make_float4(acc[i][0]+bias.x, acc[i][1]+bias.y, acc[i][2]+bias.z, acc[i][3]+bias.w);
    }
  }
}

extern "C" void kernel_launch(void* const* d_in, const int* in_sizes, int n_in,
                              void* d_out, int out_size, void* d_ws, size_t ws_size,
                              hipStream_t stream) {
  const float* ft    = (const float*)d_in[0];
  const float* Wp    = (const float*)d_in[1];
  const float* We    = (const float*)d_in[2];
  const float* a_l   = (const float*)d_in[3];
  const float* a_r   = (const float*)d_in[4];
  const float* Wv    = (const float*)d_in[5];
  const float* Wgp   = (const float*)d_in[6];
  const float* Wgate = (const float*)d_in[7];
  const float* bgate = (const float*)d_in[8];
  const float* Wtran = (const float*)d_in[9];
  const float* btran = (const float*)d_in[10];
  const int*   src   = (const int*)d_in[11];
  const int*   dst   = (const int*)d_in[12];
  float* out = (float*)d_out;

  char* p = (char*)d_ws;
  auto alloc = [&](size_t bytes)->char* { char* r = p; p += (bytes + 255) & ~(size_t)255; return r; };
  int* deg  = (int*)alloc((size_t)NN*4);
  int* cnt  = (int*)alloc((size_t)NN*4);
  int* rowp = (int*)alloc((size_t)(NN+1)*4);
  int* psum = (int*)alloc(64*4);
  int* csrc = (int*)alloc((size_t)EE*4);
  float* pf    = (float*)alloc((size_t)NN*64*4);
  float* cur1  = (float*)alloc((size_t)NN*64*4);
  float* cur2  = (float*)alloc((size_t)NN*256*4);
  float* elb   = (float*)alloc((size_t)NN*4*4);
  float* erb   = (float*)alloc((size_t)NN*4*4);
  float* pz    = (float*)alloc((size_t)NN*64*4);
  float* pool  = (float*)alloc((size_t)NN*64*4);
  float* aggcg = (float*)alloc((size_t)NN*256*4);

  hipMemsetAsync(deg, 0, (size_t)NN*4, stream);
  hipMemsetAsync(cnt, 0, (size_t)NN*4, stream);
  k_deg<<<(EE+255)/256, 256, 0, stream>>>(dst, deg);
  k_scan1<<<NB_SCAN, 256, 0, stream>>>(deg, psum);
  k_scan2<<<1, 64, 0, stream>>>(psum, NB_SCAN);
  k_scan3<<<NB_SCAN, 256, 0, stream>>>(deg, psum, rowp);
  k_fill<<<(EE+255)/256, 256, 0, stream>>>(src, dst, rowp, cnt, csrc);

  k_gemm_proj<<<(NN+63)/64, 256, 0, stream>>>(ft, Wp, pf);

  int gb = (NN+63)/64;
  // layer 0 (cur = proj_feat)
  k_nodemm2<<<gb, 256, 0, stream>>>(pf, We, Wgp, pz, pool);
  k_eler<<<NN/4, 256, 0, stream>>>(pz, a_l, a_r, elb, erb);
  k_edge<<<NN/4, 256, 0, stream>>>(rowp, csrc, elb, erb, pf, pool, Wgate, bgate, aggcg);
  k_post0<<<gb, 256, 0, stream>>>(aggcg, Wv, cur1);
  // layer 1
  k_nodemm2<<<gb, 256, 0, stream>>>(cur1, We, Wgp + 4096, pz, pool);
  k_eler<<<NN/4, 256, 0, stream>>>(pz, a_l + 256, a_r + 256, elb, erb);
  k_edge<<<NN/4, 256, 0, stream>>>(rowp, csrc, elb, erb, cur1, pool, Wgate + 768, bgate + 4, aggcg);
  k_post1<<<dim3(gb,4), 256, 0, stream>>>(aggcg, Wv + 16384, cur2);

  k_final<<<gb, 256, 0, stream>>>(pf, cur2, Wtran, btran, out);
}

// Round 3
// 1323.950 us; speedup vs baseline: 1.0092x; 1.0092x over previous
//
#include <hip/hip_runtime.h>

#define NN 50000
#define EE 800000      // 750000 random + 50000 self-loops
#define IND 512
#define HD 64
#define NB_SCAN 49     // ceil(NN/1024)

__device__ __forceinline__ float lrelu(float x, float s){ return x > 0.f ? x : s*x; }

// ---------------- CSR build (by dst) ----------------
__global__ void k_deg(const int* __restrict__ dst, int* __restrict__ deg){
  int e = blockIdx.x*256 + threadIdx.x;
  if(e < EE) atomicAdd(&deg[dst[e]], 1);
}

__global__ void k_scan1(const int* __restrict__ deg, int* __restrict__ psum){
  __shared__ int sh[256];
  int base = blockIdx.x*1024 + threadIdx.x*4;
  int s = 0;
  #pragma unroll
  for(int j=0;j<4;j++){ int i=base+j; if(i<NN) s += deg[i]; }
  sh[threadIdx.x]=s; __syncthreads();
  for(int st=128; st>0; st>>=1){ if(threadIdx.x<st) sh[threadIdx.x]+=sh[threadIdx.x+st]; __syncthreads(); }
  if(threadIdx.x==0) psum[blockIdx.x]=sh[0];
}

__global__ void k_scan2(int* __restrict__ psum, int nb){
  if(threadIdx.x==0){ int acc=0; for(int i=0;i<nb;i++){ int v=psum[i]; psum[i]=acc; acc+=v; } psum[nb]=acc; }
}

__global__ void k_scan3(const int* __restrict__ deg, const int* __restrict__ psum, int* __restrict__ rowp){
  __shared__ int sh[256];
  int t = threadIdx.x;
  int base = blockIdx.x*1024 + t*4;
  int v[4]; int s=0;
  #pragma unroll
  for(int j=0;j<4;j++){ int i=base+j; v[j] = (i<NN)?deg[i]:0; s+=v[j]; }
  sh[t]=s; __syncthreads();
  for(int st=1; st<256; st<<=1){
    int add = (t>=st)? sh[t-st] : 0;
    __syncthreads();
    sh[t] += add;
    __syncthreads();
  }
  int excl = sh[t]-s + psum[blockIdx.x];
  #pragma unroll
  for(int j=0;j<4;j++){ int i=base+j; if(i<NN){ rowp[i]=excl; excl+=v[j]; } }
  if(blockIdx.x==0 && t==0) rowp[NN] = psum[NB_SCAN];
}

__global__ void k_fill(const int* __restrict__ src, const int* __restrict__ dst,
                       const int* __restrict__ rowp, int* __restrict__ cnt, int* __restrict__ csrc){
  int e = blockIdx.x*256 + threadIdx.x;
  if(e < EE){
    int d = dst[e];
    int p = atomicAdd(&cnt[d], 1);
    csrc[rowp[d] + p] = src[e];
  }
}

// ---------------- shared GEMM tile machinery (64x64 C-tile, 256 thr, 4x4/thr) ----------------
__device__ __forceinline__ void load_A_tile(const float* __restrict__ A, int row0, int lda, int kcol0, float* As){
  int t = threadIdx.x;
  int lr = t>>2;             // row 0..63
  int lc = (t&3)*16;         // k base 0/16/32/48
  float4 a[4];
  int row = row0 + lr;
  if(row < NN){
    const float* ap = A + (size_t)row*lda + kcol0 + lc;
    a[0]=*(const float4*)ap; a[1]=*(const float4*)(ap+4); a[2]=*(const float4*)(ap+8); a[3]=*(const float4*)(ap+12);
  } else {
    a[0]=a[1]=a[2]=a[3]=make_float4(0.f,0.f,0.f,0.f);
  }
  const float* av = (const float*)a;
  #pragma unroll
  for(int q=0;q<16;q++) As[(lc+q)*68 + lr] = av[q];
}

__device__ __forceinline__ void load_B_tile(const float* __restrict__ B, int krow0, float* Bs){
  int t = threadIdx.x;
  int bk = t>>2; int lc = (t&3)*16;
  const float* bp = B + (size_t)(krow0+bk)*64 + lc;
  *(float4*)(Bs + bk*64 + lc)      = *(const float4*)bp;
  *(float4*)(Bs + bk*64 + lc + 4)  = *(const float4*)(bp+4);
  *(float4*)(Bs + bk*64 + lc + 8)  = *(const float4*)(bp+8);
  *(float4*)(Bs + bk*64 + lc + 12) = *(const float4*)(bp+12);
}

__device__ __forceinline__ void tile64_compute(const float* __restrict__ As, const float* __restrict__ Bs,
                                               float acc[4][4], int ty, int tx){
  #pragma unroll
  for(int kk=0; kk<64; kk++){
    float4 a = *(const float4*)(As + kk*68 + ty*4);
    float4 b = *(const float4*)(Bs + kk*64 + tx*4);
    acc[0][0]+=a.x*b.x; acc[0][1]+=a.x*b.y; acc[0][2]+=a.x*b.z; acc[0][3]+=a.x*b.w;
    acc[1][0]+=a.y*b.x; acc[1][1]+=a.y*b.y; acc[1][2]+=a.y*b.z; acc[1][3]+=a.y*b.w;
    acc[2][0]+=a.z*b.x; acc[2][1]+=a.z*b.y; acc[2][2]+=a.z*b.z; acc[2][3]+=a.z*b.w;
    acc[3][0]+=a.w*b.x; acc[3][1]+=a.w*b.y; acc[3][2]+=a.w*b.z; acc[3][3]+=a.w*b.w;
  }
}

// proj_feat = ft @ Wp   [NN,512]@[512,64]
__global__ __launch_bounds__(256) void k_gemm_proj(const float* __restrict__ A, const float* __restrict__ B, float* __restrict__ C){
  __shared__ float As[64*68];
  __shared__ float Bs[64*64];
  int row0 = blockIdx.x*64;
  int ty = threadIdx.x>>4, tx = threadIdx.x&15;
  float acc[4][4] = {};
  #pragma unroll 1
  for(int kt=0; kt<IND; kt+=64){
    __syncthreads();
    load_A_tile(A, row0, IND, kt, As);
    load_B_tile(B, kt, Bs);
    __syncthreads();
    tile64_compute(As, Bs, acc, ty, tx);
  }
  #pragma unroll
  for(int i=0;i<4;i++){
    int row = row0 + ty*4 + i;
    if(row < NN) *(float4*)(C + (size_t)row*64 + tx*4) = make_float4(acc[i][0],acc[i][1],acc[i][2],acc[i][3]);
  }
}

// node matmuls merged: proj_z = cur@We AND pooled = cur@Wg — LOOPED (spill guard)
__global__ __launch_bounds__(256) void k_nodemm2(const float* __restrict__ cur, const float* __restrict__ We,
                                                 const float* __restrict__ Wg,
                                                 float* __restrict__ projz, float* __restrict__ pooled){
  __shared__ float As[64*68];
  __shared__ float Bs[64*64];
  int row0 = blockIdx.x*64;
  int ty = threadIdx.x>>4, tx = threadIdx.x&15;
  load_A_tile(cur, row0, 64, 0, As);
  #pragma unroll 1
  for(int bi=0; bi<2; ++bi){
    const float* B = bi ? Wg : We;
    float* C = bi ? pooled : projz;
    __syncthreads();                 // iter0: As ready; iter1: prior compute done with Bs
    load_B_tile(B, 0, Bs);
    __syncthreads();
    float acc[4][4] = {};
    tile64_compute(As, Bs, acc, ty, tx);
    #pragma unroll
    for(int i=0;i<4;i++){
      int row = row0 + ty*4 + i;
      if(row < NN) *(float4*)(C + (size_t)row*64 + tx*4) = make_float4(acc[i][0],acc[i][1],acc[i][2],acc[i][3]);
    }
  }
}

// el/er per node per head (wave per node, butterfly reduce)
__global__ __launch_bounds__(256) void k_eler(const float* __restrict__ projz, const float* __restrict__ al,
                                              const float* __restrict__ ar, float* __restrict__ el, float* __restrict__ er){
  int wid = threadIdx.x>>6, lane = threadIdx.x&63;
  int n = blockIdx.x*4 + wid;
  if(n >= NN) return;
  float z = projz[(size_t)n*64 + lane];
  #pragma unroll
  for(int h=0; h<4; h++){
    float pl = z*al[h*64+lane];
    float pr = z*ar[h*64+lane];
    #pragma unroll
    for(int st=32; st; st>>=1){ pl += __shfl_xor(pl, st, 64); pr += __shfl_xor(pr, st, 64); }
    if(lane==0){ el[(size_t)n*4+h]=pl; er[(size_t)n*4+h]=pr; }
  }
}

// per-node edge kernel: softmax over edges + per-head weighted sum of CUR (pre-Wv) + GaAN gate
__global__ __launch_bounds__(256) void k_edge(const int* __restrict__ rowp, const int* __restrict__ csrc,
    const float* __restrict__ el, const float* __restrict__ er, const float* __restrict__ cur,
    const float* __restrict__ pooled,
    const float* __restrict__ Wg, const float* __restrict__ bg, float* __restrict__ aggcg)
{
  int wid = threadIdx.x>>6, lane = threadIdx.x&63;
  int d = blockIdx.x*4 + wid;
  if(d >= NN) return;
  int e0 = rowp[d], e1 = rowp[d+1];
  float4 erd = *(const float4*)(er + (size_t)d*4);
  float m0=-1e30f, m1=-1e30f, m2=-1e30f, m3=-1e30f;
  for(int e=e0+lane; e<e1; e+=64){
    int s = csrc[e];
    float4 ev = *(const float4*)(el + (size_t)s*4);
    m0 = fmaxf(m0, lrelu(ev.x+erd.x, 0.2f));
    m1 = fmaxf(m1, lrelu(ev.y+erd.y, 0.2f));
    m2 = fmaxf(m2, lrelu(ev.z+erd.z, 0.2f));
    m3 = fmaxf(m3, lrelu(ev.w+erd.w, 0.2f));
  }
  #pragma unroll
  for(int st=32; st; st>>=1){
    m0=fmaxf(m0,__shfl_xor(m0,st,64)); m1=fmaxf(m1,__shfl_xor(m1,st,64));
    m2=fmaxf(m2,__shfl_xor(m2,st,64)); m3=fmaxf(m3,__shfl_xor(m3,st,64));
  }
  float n0=0,n1=0,n2=0,n3=0, den0=0,den1=0,den2=0,den3=0, mn=0, mxp=-1e30f;
  for(int e=e0; e<e1; ++e){
    int s = csrc[e];                                   // wave-uniform
    float4 ev = *(const float4*)(el + (size_t)s*4);    // wave-uniform
    float x0 = __expf(lrelu(ev.x+erd.x,0.2f)-m0);
    float x1 = __expf(lrelu(ev.y+erd.y,0.2f)-m1);
    float x2 = __expf(lrelu(ev.z+erd.z,0.2f)-m2);
    float x3 = __expf(lrelu(ev.w+erd.w,0.2f)-m3);
    den0+=x0; den1+=x1; den2+=x2; den3+=x3;
    float cv = cur[(size_t)s*64 + lane];
    n0 += x0*cv; n1 += x1*cv; n2 += x2*cv; n3 += x3*cv;
    mn += cv;
    mxp = fmaxf(mxp, pooled[(size_t)s*64 + lane]);
  }
  float cd  = cur[(size_t)d*64 + lane];
  float mnn = mn / (float)(e1-e0);
  float4 w0 = *(const float4*)(Wg + lane*4);
  float4 w1 = *(const float4*)(Wg + (64+lane)*4);
  float4 w2 = *(const float4*)(Wg + (128+lane)*4);
  float g0 = cd*w0.x + mxp*w1.x + mnn*w2.x;
  float g1 = cd*w0.y + mxp*w1.y + mnn*w2.y;
  float g2 = cd*w0.z + mxp*w1.z + mnn*w2.z;
  float g3 = cd*w0.w + mxp*w1.w + mnn*w2.w;
  #pragma unroll
  for(int st=32; st; st>>=1){
    g0+=__shfl_xor(g0,st,64); g1+=__shfl_xor(g1,st,64);
    g2+=__shfl_xor(g2,st,64); g3+=__shfl_xor(g3,st,64);
  }
  g0 = 1.f/(1.f+__expf(-(g0+bg[0])));
  g1 = 1.f/(1.f+__expf(-(g1+bg[1])));
  g2 = 1.f/(1.f+__expf(-(g2+bg[2])));
  g3 = 1.f/(1.f+__expf(-(g3+bg[3])));
  float* od = aggcg + (size_t)d*256;
  od[lane]       = g0 * n0/den0;
  od[64 + lane]  = g1 * n1/den1;
  od[128 + lane] = g2 * n2/den2;
  od[192 + lane] = g3 * n3/den3;
}

// layer0 post: cur1 = lrelu(0.25 * aggcg[N,256] @ WvStack[256,64])
__global__ __launch_bounds__(256) void k_post0(const float* __restrict__ A, const float* __restrict__ B, float* __restrict__ C){
  __shared__ float As[64*68];
  __shared__ float Bs[64*64];
  int row0 = blockIdx.x*64;
  int ty = threadIdx.x>>4, tx = threadIdx.x&15;
  float acc[4][4] = {};
  #pragma unroll 1
  for(int kt=0; kt<256; kt+=64){
    __syncthreads();
    load_A_tile(A, row0, 256, kt, As);
    load_B_tile(B, kt, Bs);
    __syncthreads();
    tile64_compute(As, Bs, acc, ty, tx);
  }
  #pragma unroll
  for(int i=0;i<4;i++){
    int row = row0 + ty*4 + i;
    if(row < NN) *(float4*)(C + (size_t)row*64 + tx*4) =
      make_float4(lrelu(0.25f*acc[i][0],0.01f), lrelu(0.25f*acc[i][1],0.01f),
                  lrelu(0.25f*acc[i][2],0.01f), lrelu(0.25f*acc[i][3],0.01f));
  }
}

// layer1 post: cur2[:, h*64:(h+1)*64] = lrelu(aggcg[:, h*64:]@Wv1[h]) — LOOPED over heads (spill guard)
__global__ __launch_bounds__(256) void k_post1(const float* __restrict__ aggcg, const float* __restrict__ Wv1, float* __restrict__ cur2){
  __shared__ float As[64*68];
  __shared__ float Bs[64*64];
  int row0 = blockIdx.x*64;
  int ty = threadIdx.x>>4, tx = threadIdx.x&15;
  #pragma unroll 1
  for(int h=0; h<4; ++h){
    __syncthreads();                 // prior iter's compute done with As/Bs
    load_A_tile(aggcg + h*64, row0, 256, 0, As);
    load_B_tile(Wv1 + (size_t)h*4096, 0, Bs);
    __syncthreads();
    float acc[4][4] = {};
    tile64_compute(As, Bs, acc, ty, tx);
    #pragma unroll
    for(int i=0;i<4;i++){
      int row = row0 + ty*4 + i;
      if(row < NN) *(float4*)(cur2 + (size_t)row*256 + h*64 + tx*4) =
        make_float4(lrelu(acc[i][0],0.01f), lrelu(acc[i][1],0.01f),
                    lrelu(acc[i][2],0.01f), lrelu(acc[i][3],0.01f));
    }
  }
}

// out = concat(proj_feat, cur2) @ Wtran + btran   (K=320)
__global__ __launch_bounds__(256) void k_final(const float* __restrict__ pf, const float* __restrict__ cur2,
                                               const float* __restrict__ Wt, const float* __restrict__ bt,
                                               float* __restrict__ C){
  __shared__ float As[64*68];
  __shared__ float Bs[64*64];
  int row0 = blockIdx.x*64;
  int ty = threadIdx.x>>4, tx = threadIdx.x&15;
  float acc[4][4] = {};
  #pragma unroll 1
  for(int kt=0; kt<320; kt+=64){
    __syncthreads();
    if(kt==0) load_A_tile(pf, row0, 64, 0, As);
    else      load_A_tile(cur2, row0, 256, kt-64, As);
    load_B_tile(Wt, kt, Bs);
    __syncthreads();
    tile64_compute(As, Bs, acc, ty, tx);
  }
  float4 bias = *(const float4*)(bt + tx*4);
  #pragma unroll
  for(int i=0;i<4;i++){
    int row = row0 + ty*4 + i;
    if(row < NN){
      *(float4*)(C + (size_t)row*64 + tx*4) =
        make_float4(acc[i][0]+bias.x, acc[i][1]+bias.y, acc[i][2]+bias.z, acc[i][3]+bias.w);
    }
  }
}

extern "C" void kernel_launch(void* const* d_in, const int* in_sizes, int n_in,
                              void* d_out, int out_size, void* d_ws, size_t ws_size,
                              hipStream_t stream) {
  const float* ft    = (const float*)d_in[0];
  const float* Wp    = (const float*)d_in[1];
  const float* We    = (const float*)d_in[2];
  const float* a_l   = (const float*)d_in[3];
  const float* a_r   = (const float*)d_in[4];
  const float* Wv    = (const float*)d_in[5];
  const float* Wgp   = (const float*)d_in[6];
  const float* Wgate = (const float*)d_in[7];
  const float* bgate = (const float*)d_in[8];
  const float* Wtran = (const float*)d_in[9];
  const float* btran = (const float*)d_in[10];
  const int*   src   = (const int*)d_in[11];
  const int*   dst   = (const int*)d_in[12];
  float* out = (float*)d_out;

  char* p = (char*)d_ws;
  auto alloc = [&](size_t bytes)->char* { char* r = p; p += (bytes + 255) & ~(size_t)255; return r; };
  int* deg  = (int*)alloc((size_t)NN*4);
  int* cnt  = (int*)alloc((size_t)NN*4);
  int* rowp = (int*)alloc((size_t)(NN+1)*4);
  int* psum = (int*)alloc(64*4);
  int* csrc = (int*)alloc((size_t)EE*4);
  float* pf    = (float*)alloc((size_t)NN*64*4);
  float* cur1  = (float*)alloc((size_t)NN*64*4);
  float* cur2  = (float*)alloc((size_t)NN*256*4);
  float* elb   = (float*)alloc((size_t)NN*4*4);
  float* erb   = (float*)alloc((size_t)NN*4*4);
  float* pz    = (float*)alloc((size_t)NN*64*4);
  float* pool  = (float*)alloc((size_t)NN*64*4);
  float* aggcg = (float*)alloc((size_t)NN*256*4);

  hipMemsetAsync(deg, 0, (size_t)NN*4, stream);
  hipMemsetAsync(cnt, 0, (size_t)NN*4, stream);
  k_deg<<<(EE+255)/256, 256, 0, stream>>>(dst, deg);
  k_scan1<<<NB_SCAN, 256, 0, stream>>>(deg, psum);
  k_scan2<<<1, 64, 0, stream>>>(psum, NB_SCAN);
  k_scan3<<<NB_SCAN, 256, 0, stream>>>(deg, psum, rowp);
  k_fill<<<(EE+255)/256, 256, 0, stream>>>(src, dst, rowp, cnt, csrc);

  k_gemm_proj<<<(NN+63)/64, 256, 0, stream>>>(ft, Wp, pf);

  int gb = (NN+63)/64;
  // layer 0 (cur = proj_feat)
  k_nodemm2<<<gb, 256, 0, stream>>>(pf, We, Wgp, pz, pool);
  k_eler<<<NN/4, 256, 0, stream>>>(pz, a_l, a_r, elb, erb);
  k_edge<<<NN/4, 256, 0, stream>>>(rowp, csrc, elb, erb, pf, pool, Wgate, bgate, aggcg);
  k_post0<<<gb, 256, 0, stream>>>(aggcg, Wv, cur1);
  // layer 1
  k_nodemm2<<<gb, 256, 0, stream>>>(cur1, We, Wgp + 4096, pz, pool);
  k_eler<<<NN/4, 256, 0, stream>>>(pz, a_l + 256, a_r + 256, elb, erb);
  k_edge<<<NN/4, 256, 0, stream>>>(rowp, csrc, elb, erb, cur1, pool, Wgate + 768, bgate + 4, aggcg);
  k_post1<<<gb, 256, 0, stream>>>(aggcg, Wv + 16384, cur2);

  k_final<<<gb, 256, 0, stream>>>(pf, cur2, Wtran, btran, out);
}

// Round 4
// 710.696 us; speedup vs baseline: 1.8801x; 1.8629x over previous
//
#include <hip/hip_runtime.h>

#define NN 50000
#define EE 800000      // 750000 random + 50000 self-loops
#define IND 512
#define HD 64
#define NB_SCAN 49     // ceil(NN/1024)

__device__ __forceinline__ float lrelu(float x, float s){ return x > 0.f ? x : s*x; }

// ---------------- CSR build (by dst) ----------------
__global__ void k_deg(const int* __restrict__ dst, int* __restrict__ deg){
  int e = blockIdx.x*256 + threadIdx.x;
  if(e < EE) atomicAdd(&deg[dst[e]], 1);
}

__global__ void k_scan1(const int* __restrict__ deg, int* __restrict__ psum){
  __shared__ int sh[256];
  int base = blockIdx.x*1024 + threadIdx.x*4;
  int s = 0;
  #pragma unroll
  for(int j=0;j<4;j++){ int i=base+j; if(i<NN) s += deg[i]; }
  sh[threadIdx.x]=s; __syncthreads();
  for(int st=128; st>0; st>>=1){ if(threadIdx.x<st) sh[threadIdx.x]+=sh[threadIdx.x+st]; __syncthreads(); }
  if(threadIdx.x==0) psum[blockIdx.x]=sh[0];
}

__global__ void k_scan2(int* __restrict__ psum, int nb){
  if(threadIdx.x==0){ int acc=0; for(int i=0;i<nb;i++){ int v=psum[i]; psum[i]=acc; acc+=v; } psum[nb]=acc; }
}

__global__ void k_scan3(const int* __restrict__ deg, const int* __restrict__ psum, int* __restrict__ rowp){
  __shared__ int sh[256];
  int t = threadIdx.x;
  int base = blockIdx.x*1024 + t*4;
  int v[4]; int s=0;
  #pragma unroll
  for(int j=0;j<4;j++){ int i=base+j; v[j] = (i<NN)?deg[i]:0; s+=v[j]; }
  sh[t]=s; __syncthreads();
  for(int st=1; st<256; st<<=1){
    int add = (t>=st)? sh[t-st] : 0;
    __syncthreads();
    sh[t] += add;
    __syncthreads();
  }
  int excl = sh[t]-s + psum[blockIdx.x];
  #pragma unroll
  for(int j=0;j<4;j++){ int i=base+j; if(i<NN){ rowp[i]=excl; excl+=v[j]; } }
  if(blockIdx.x==0 && t==0) rowp[NN] = psum[NB_SCAN];
}

__global__ void k_fill(const int* __restrict__ src, const int* __restrict__ dst,
                       const int* __restrict__ rowp, int* __restrict__ cnt, int* __restrict__ csrc){
  int e = blockIdx.x*256 + threadIdx.x;
  if(e < EE){
    int d = dst[e];
    int p = atomicAdd(&cnt[d], 1);
    csrc[rowp[d] + p] = src[e];
  }
}

// ---------------- shared GEMM tile machinery (64x64 C-tile, 256 thr, 4x4/thr) ----------------
// As stored transposed [k][row], stride 68. No local arrays (SROA hazard) — named float4s.
__device__ __forceinline__ void load_A_tile(const float* __restrict__ A, int row0, int lda, int kcol0, float* As){
  int t = threadIdx.x;
  int lr = t>>2;             // row 0..63
  int lc = (t&3)*16;         // k base 0/16/32/48
  float4 a0,a1,a2,a3;
  int row = row0 + lr;
  if(row < NN){
    const float* ap = A + (size_t)row*lda + kcol0 + lc;
    a0=*(const float4*)ap; a1=*(const float4*)(ap+4); a2=*(const float4*)(ap+8); a3=*(const float4*)(ap+12);
  } else {
    a0=a1=a2=a3=make_float4(0.f,0.f,0.f,0.f);
  }
  float* d = As + (size_t)lc*68 + lr;
  d[0*68]=a0.x;  d[1*68]=a0.y;  d[2*68]=a0.z;  d[3*68]=a0.w;
  d[4*68]=a1.x;  d[5*68]=a1.y;  d[6*68]=a1.z;  d[7*68]=a1.w;
  d[8*68]=a2.x;  d[9*68]=a2.y;  d[10*68]=a2.z; d[11*68]=a2.w;
  d[12*68]=a3.x; d[13*68]=a3.y; d[14*68]=a3.z; d[15*68]=a3.w;
}

__device__ __forceinline__ void load_B_tile(const float* __restrict__ B, int krow0, float* Bs){
  int t = threadIdx.x;
  int bk = t>>2; int lc = (t&3)*16;
  const float* bp = B + (size_t)(krow0+bk)*64 + lc;
  *(float4*)(Bs + bk*64 + lc)      = *(const float4*)bp;
  *(float4*)(Bs + bk*64 + lc + 4)  = *(const float4*)(bp+4);
  *(float4*)(Bs + bk*64 + lc + 8)  = *(const float4*)(bp+8);
  *(float4*)(Bs + bk*64 + lc + 12) = *(const float4*)(bp+12);
}

// partial unroll: keeps live set ~60 VGPR (acc16 + 2x4 staged float4 + addrs)
__device__ __forceinline__ void tile64_compute(const float* __restrict__ As, const float* __restrict__ Bs,
                                               float acc[4][4], int ty, int tx){
  #pragma unroll 4
  for(int kk=0; kk<64; kk++){
    float4 a = *(const float4*)(As + kk*68 + ty*4);
    float4 b = *(const float4*)(Bs + kk*64 + tx*4);
    acc[0][0]+=a.x*b.x; acc[0][1]+=a.x*b.y; acc[0][2]+=a.x*b.z; acc[0][3]+=a.x*b.w;
    acc[1][0]+=a.y*b.x; acc[1][1]+=a.y*b.y; acc[1][2]+=a.y*b.z; acc[1][3]+=a.y*b.w;
    acc[2][0]+=a.z*b.x; acc[2][1]+=a.z*b.y; acc[2][2]+=a.z*b.z; acc[2][3]+=a.z*b.w;
    acc[3][0]+=a.w*b.x; acc[3][1]+=a.w*b.y; acc[3][2]+=a.w*b.z; acc[3][3]+=a.w*b.w;
  }
}

// proj_feat = ft @ Wp   [NN,512]@[512,64]
__global__ __launch_bounds__(256, 4) void k_gemm_proj(const float* __restrict__ A, const float* __restrict__ B, float* __restrict__ C){
  __shared__ float As[64*68];
  __shared__ float Bs[64*64];
  int row0 = blockIdx.x*64;
  int ty = threadIdx.x>>4, tx = threadIdx.x&15;
  float acc[4][4] = {};
  #pragma unroll 1
  for(int kt=0; kt<IND; kt+=64){
    __syncthreads();
    load_A_tile(A, row0, IND, kt, As);
    load_B_tile(B, kt, Bs);
    __syncthreads();
    tile64_compute(As, Bs, acc, ty, tx);
  }
  #pragma unroll
  for(int i=0;i<4;i++){
    int row = row0 + ty*4 + i;
    if(row < NN) *(float4*)(C + (size_t)row*64 + tx*4) = make_float4(acc[i][0],acc[i][1],acc[i][2],acc[i][3]);
  }
}

// node matmuls merged: proj_z = cur@We AND pooled = cur@Wg
__global__ __launch_bounds__(256, 4) void k_nodemm2(const float* __restrict__ cur, const float* __restrict__ We,
                                                    const float* __restrict__ Wg,
                                                    float* __restrict__ projz, float* __restrict__ pooled){
  __shared__ float As[64*68];
  __shared__ float Bs[64*64];
  int row0 = blockIdx.x*64;
  int ty = threadIdx.x>>4, tx = threadIdx.x&15;
  load_A_tile(cur, row0, 64, 0, As);
  #pragma unroll 1
  for(int bi=0; bi<2; ++bi){
    const float* B = bi ? Wg : We;
    float* C = bi ? pooled : projz;
    __syncthreads();                 // iter0: As ready; iter1: prior compute done with Bs
    load_B_tile(B, 0, Bs);
    __syncthreads();
    float acc[4][4] = {};
    tile64_compute(As, Bs, acc, ty, tx);
    #pragma unroll
    for(int i=0;i<4;i++){
      int row = row0 + ty*4 + i;
      if(row < NN) *(float4*)(C + (size_t)row*64 + tx*4) = make_float4(acc[i][0],acc[i][1],acc[i][2],acc[i][3]);
    }
  }
}

// el/er per node per head (wave per node, butterfly reduce)
__global__ __launch_bounds__(256) void k_eler(const float* __restrict__ projz, const float* __restrict__ al,
                                              const float* __restrict__ ar, float* __restrict__ el, float* __restrict__ er){
  int wid = threadIdx.x>>6, lane = threadIdx.x&63;
  int n = blockIdx.x*4 + wid;
  if(n >= NN) return;
  float z = projz[(size_t)n*64 + lane];
  #pragma unroll
  for(int h=0; h<4; h++){
    float pl = z*al[h*64+lane];
    float pr = z*ar[h*64+lane];
    #pragma unroll
    for(int st=32; st; st>>=1){ pl += __shfl_xor(pl, st, 64); pr += __shfl_xor(pr, st, 64); }
    if(lane==0){ el[(size_t)n*4+h]=pl; er[(size_t)n*4+h]=pr; }
  }
}

// per-node edge kernel: softmax over edges + per-head weighted sum of CUR (pre-Wv) + GaAN gate
__global__ __launch_bounds__(256) void k_edge(const int* __restrict__ rowp, const int* __restrict__ csrc,
    const float* __restrict__ el, const float* __restrict__ er, const float* __restrict__ cur,
    const float* __restrict__ pooled,
    const float* __restrict__ Wg, const float* __restrict__ bg, float* __restrict__ aggcg)
{
  int wid = threadIdx.x>>6, lane = threadIdx.x&63;
  int d = blockIdx.x*4 + wid;
  if(d >= NN) return;
  int e0 = rowp[d], e1 = rowp[d+1];
  float4 erd = *(const float4*)(er + (size_t)d*4);
  float m0=-1e30f, m1=-1e30f, m2=-1e30f, m3=-1e30f;
  for(int e=e0+lane; e<e1; e+=64){
    int s = csrc[e];
    float4 ev = *(const float4*)(el + (size_t)s*4);
    m0 = fmaxf(m0, lrelu(ev.x+erd.x, 0.2f));
    m1 = fmaxf(m1, lrelu(ev.y+erd.y, 0.2f));
    m2 = fmaxf(m2, lrelu(ev.z+erd.z, 0.2f));
    m3 = fmaxf(m3, lrelu(ev.w+erd.w, 0.2f));
  }
  #pragma unroll
  for(int st=32; st; st>>=1){
    m0=fmaxf(m0,__shfl_xor(m0,st,64)); m1=fmaxf(m1,__shfl_xor(m1,st,64));
    m2=fmaxf(m2,__shfl_xor(m2,st,64)); m3=fmaxf(m3,__shfl_xor(m3,st,64));
  }
  float n0=0,n1=0,n2=0,n3=0, den0=0,den1=0,den2=0,den3=0, mn=0, mxp=-1e30f;
  for(int e=e0; e<e1; ++e){
    int s = csrc[e];                                   // wave-uniform
    float4 ev = *(const float4*)(el + (size_t)s*4);    // wave-uniform
    float x0 = __expf(lrelu(ev.x+erd.x,0.2f)-m0);
    float x1 = __expf(lrelu(ev.y+erd.y,0.2f)-m1);
    float x2 = __expf(lrelu(ev.z+erd.z,0.2f)-m2);
    float x3 = __expf(lrelu(ev.w+erd.w,0.2f)-m3);
    den0+=x0; den1+=x1; den2+=x2; den3+=x3;
    float cv = cur[(size_t)s*64 + lane];
    n0 += x0*cv; n1 += x1*cv; n2 += x2*cv; n3 += x3*cv;
    mn += cv;
    mxp = fmaxf(mxp, pooled[(size_t)s*64 + lane]);
  }
  float cd  = cur[(size_t)d*64 + lane];
  float mnn = mn / (float)(e1-e0);
  float4 w0 = *(const float4*)(Wg + lane*4);
  float4 w1 = *(const float4*)(Wg + (64+lane)*4);
  float4 w2 = *(const float4*)(Wg + (128+lane)*4);
  float g0 = cd*w0.x + mxp*w1.x + mnn*w2.x;
  float g1 = cd*w0.y + mxp*w1.y + mnn*w2.y;
  float g2 = cd*w0.z + mxp*w1.z + mnn*w2.z;
  float g3 = cd*w0.w + mxp*w1.w + mnn*w2.w;
  #pragma unroll
  for(int st=32; st; st>>=1){
    g0+=__shfl_xor(g0,st,64); g1+=__shfl_xor(g1,st,64);
    g2+=__shfl_xor(g2,st,64); g3+=__shfl_xor(g3,st,64);
  }
  g0 = 1.f/(1.f+__expf(-(g0+bg[0])));
  g1 = 1.f/(1.f+__expf(-(g1+bg[1])));
  g2 = 1.f/(1.f+__expf(-(g2+bg[2])));
  g3 = 1.f/(1.f+__expf(-(g3+bg[3])));
  float* od = aggcg + (size_t)d*256;
  od[lane]       = g0 * n0/den0;
  od[64 + lane]  = g1 * n1/den1;
  od[128 + lane] = g2 * n2/den2;
  od[192 + lane] = g3 * n3/den3;
}

// layer0 post: cur1 = lrelu(0.25 * aggcg[N,256] @ WvStack[256,64])
__global__ __launch_bounds__(256, 4) void k_post0(const float* __restrict__ A, const float* __restrict__ B, float* __restrict__ C){
  __shared__ float As[64*68];
  __shared__ float Bs[64*64];
  int row0 = blockIdx.x*64;
  int ty = threadIdx.x>>4, tx = threadIdx.x&15;
  float acc[4][4] = {};
  #pragma unroll 1
  for(int kt=0; kt<256; kt+=64){
    __syncthreads();
    load_A_tile(A, row0, 256, kt, As);
    load_B_tile(B, kt, Bs);
    __syncthreads();
    tile64_compute(As, Bs, acc, ty, tx);
  }
  #pragma unroll
  for(int i=0;i<4;i++){
    int row = row0 + ty*4 + i;
    if(row < NN) *(float4*)(C + (size_t)row*64 + tx*4) =
      make_float4(lrelu(0.25f*acc[i][0],0.01f), lrelu(0.25f*acc[i][1],0.01f),
                  lrelu(0.25f*acc[i][2],0.01f), lrelu(0.25f*acc[i][3],0.01f));
  }
}

// layer1 post: cur2[:, h*64:(h+1)*64] = lrelu(aggcg[:, h*64:]@Wv1[h]) — looped over heads
__global__ __launch_bounds__(256, 4) void k_post1(const float* __restrict__ aggcg, const float* __restrict__ Wv1, float* __restrict__ cur2){
  __shared__ float As[64*68];
  __shared__ float Bs[64*64];
  int row0 = blockIdx.x*64;
  int ty = threadIdx.x>>4, tx = threadIdx.x&15;
  #pragma unroll 1
  for(int h=0; h<4; ++h){
    __syncthreads();                 // prior iter's compute done with As/Bs
    load_A_tile(aggcg + h*64, row0, 256, 0, As);
    load_B_tile(Wv1 + (size_t)h*4096, 0, Bs);
    __syncthreads();
    float acc[4][4] = {};
    tile64_compute(As, Bs, acc, ty, tx);
    #pragma unroll
    for(int i=0;i<4;i++){
      int row = row0 + ty*4 + i;
      if(row < NN) *(float4*)(cur2 + (size_t)row*256 + h*64 + tx*4) =
        make_float4(lrelu(acc[i][0],0.01f), lrelu(acc[i][1],0.01f),
                    lrelu(acc[i][2],0.01f), lrelu(acc[i][3],0.01f));
    }
  }
}

// out = concat(proj_feat, cur2) @ Wtran + btran   (K=320)
__global__ __launch_bounds__(256, 4) void k_final(const float* __restrict__ pf, const float* __restrict__ cur2,
                                                  const float* __restrict__ Wt, const float* __restrict__ bt,
                                                  float* __restrict__ C){
  __shared__ float As[64*68];
  __shared__ float Bs[64*64];
  int row0 = blockIdx.x*64;
  int ty = threadIdx.x>>4, tx = threadIdx.x&15;
  float acc[4][4] = {};
  #pragma unroll 1
  for(int kt=0; kt<320; kt+=64){
    __syncthreads();
    if(kt==0) load_A_tile(pf, row0, 64, 0, As);
    else      load_A_tile(cur2, row0, 256, kt-64, As);
    load_B_tile(Wt, kt, Bs);
    __syncthreads();
    tile64_compute(As, Bs, acc, ty, tx);
  }
  float4 bias = *(const float4*)(bt + tx*4);
  #pragma unroll
  for(int i=0;i<4;i++){
    int row = row0 + ty*4 + i;
    if(row < NN){
      *(float4*)(C + (size_t)row*64 + tx*4) =
        make_float4(acc[i][0]+bias.x, acc[i][1]+bias.y, acc[i][2]+bias.z, acc[i][3]+bias.w);
    }
  }
}

extern "C" void kernel_launch(void* const* d_in, const int* in_sizes, int n_in,
                              void* d_out, int out_size, void* d_ws, size_t ws_size,
                              hipStream_t stream) {
  const float* ft    = (const float*)d_in[0];
  const float* Wp    = (const float*)d_in[1];
  const float* We    = (const float*)d_in[2];
  const float* a_l   = (const float*)d_in[3];
  const float* a_r   = (const float*)d_in[4];
  const float* Wv    = (const float*)d_in[5];
  const float* Wgp   = (const float*)d_in[6];
  const float* Wgate = (const float*)d_in[7];
  const float* bgate = (const float*)d_in[8];
  const float* Wtran = (const float*)d_in[9];
  const float* btran = (const float*)d_in[10];
  const int*   src   = (const int*)d_in[11];
  const int*   dst   = (const int*)d_in[12];
  float* out = (float*)d_out;

  char* p = (char*)d_ws;
  auto alloc = [&](size_t bytes)->char* { char* r = p; p += (bytes + 255) & ~(size_t)255; return r; };
  int* deg  = (int*)alloc((size_t)NN*4);
  int* cnt  = (int*)alloc((size_t)NN*4);
  int* rowp = (int*)alloc((size_t)(NN+1)*4);
  int* psum = (int*)alloc(64*4);
  int* csrc = (int*)alloc((size_t)EE*4);
  float* pf    = (float*)alloc((size_t)NN*64*4);
  float* cur1  = (float*)alloc((size_t)NN*64*4);
  float* cur2  = (float*)alloc((size_t)NN*256*4);
  float* elb   = (float*)alloc((size_t)NN*4*4);
  float* erb   = (float*)alloc((size_t)NN*4*4);
  float* pz    = (float*)alloc((size_t)NN*64*4);
  float* pool  = (float*)alloc((size_t)NN*64*4);
  float* aggcg = (float*)alloc((size_t)NN*256*4);

  hipMemsetAsync(deg, 0, (size_t)NN*4, stream);
  hipMemsetAsync(cnt, 0, (size_t)NN*4, stream);
  k_deg<<<(EE+255)/256, 256, 0, stream>>>(dst, deg);
  k_scan1<<<NB_SCAN, 256, 0, stream>>>(deg, psum);
  k_scan2<<<1, 64, 0, stream>>>(psum, NB_SCAN);
  k_scan3<<<NB_SCAN, 256, 0, stream>>>(deg, psum, rowp);
  k_fill<<<(EE+255)/256, 256, 0, stream>>>(src, dst, rowp, cnt, csrc);

  k_gemm_proj<<<(NN+63)/64, 256, 0, stream>>>(ft, Wp, pf);

  int gb = (NN+63)/64;
  // layer 0 (cur = proj_feat)
  k_nodemm2<<<gb, 256, 0, stream>>>(pf, We, Wgp, pz, pool);
  k_eler<<<NN/4, 256, 0, stream>>>(pz, a_l, a_r, elb, erb);
  k_edge<<<NN/4, 256, 0, stream>>>(rowp, csrc, elb, erb, pf, pool, Wgate, bgate, aggcg);
  k_post0<<<gb, 256, 0, stream>>>(aggcg, Wv, cur1);
  // layer 1
  k_nodemm2<<<gb, 256, 0, stream>>>(cur1, We, Wgp + 4096, pz, pool);
  k_eler<<<NN/4, 256, 0, stream>>>(pz, a_l + 256, a_r + 256, elb, erb);
  k_edge<<<NN/4, 256, 0, stream>>>(rowp, csrc, elb, erb, cur1, pool, Wgate + 768, bgate + 4, aggcg);
  k_post1<<<gb, 256, 0, stream>>>(aggcg, Wv + 16384, cur2);

  k_final<<<gb, 256, 0, stream>>>(pf, cur2, Wtran, btran, out);
}

// Round 5
// 645.248 us; speedup vs baseline: 2.0707x; 1.1014x over previous
//
#include <hip/hip_runtime.h>

#define NN 50000
#define EE 800000      // 750000 random + 50000 self-loops
#define IND 512
#define HD 64
#define NB_SCAN 49     // ceil(NN/1024)

__device__ __forceinline__ float lrelu(float x, float s){ return x > 0.f ? x : s*x; }

// ---------------- CSR build (by dst) ----------------
__global__ void k_deg(const int* __restrict__ dst, int* __restrict__ deg){
  int e = blockIdx.x*256 + threadIdx.x;
  if(e < EE) atomicAdd(&deg[dst[e]], 1);
}

__global__ void k_scan1(const int* __restrict__ deg, int* __restrict__ psum){
  __shared__ int sh[256];
  int base = blockIdx.x*1024 + threadIdx.x*4;
  int s = 0;
  #pragma unroll
  for(int j=0;j<4;j++){ int i=base+j; if(i<NN) s += deg[i]; }
  sh[threadIdx.x]=s; __syncthreads();
  for(int st=128; st>0; st>>=1){ if(threadIdx.x<st) sh[threadIdx.x]+=sh[threadIdx.x+st]; __syncthreads(); }
  if(threadIdx.x==0) psum[blockIdx.x]=sh[0];
}

__global__ void k_scan2(int* __restrict__ psum, int nb){
  if(threadIdx.x==0){ int acc=0; for(int i=0;i<nb;i++){ int v=psum[i]; psum[i]=acc; acc+=v; } psum[nb]=acc; }
}

__global__ void k_scan3(const int* __restrict__ deg, const int* __restrict__ psum, int* __restrict__ rowp){
  __shared__ int sh[256];
  int t = threadIdx.x;
  int base = blockIdx.x*1024 + t*4;
  int v[4]; int s=0;
  #pragma unroll
  for(int j=0;j<4;j++){ int i=base+j; v[j] = (i<NN)?deg[i]:0; s+=v[j]; }
  sh[t]=s; __syncthreads();
  for(int st=1; st<256; st<<=1){
    int add = (t>=st)? sh[t-st] : 0;
    __syncthreads();
    sh[t] += add;
    __syncthreads();
  }
  int excl = sh[t]-s + psum[blockIdx.x];
  #pragma unroll
  for(int j=0;j<4;j++){ int i=base+j; if(i<NN){ rowp[i]=excl; excl+=v[j]; } }
  if(blockIdx.x==0 && t==0) rowp[NN] = psum[NB_SCAN];
}

__global__ void k_fill(const int* __restrict__ src, const int* __restrict__ dst,
                       const int* __restrict__ rowp, int* __restrict__ cnt, int* __restrict__ csrc){
  int e = blockIdx.x*256 + threadIdx.x;
  if(e < EE){
    int d = dst[e];
    int p = atomicAdd(&cnt[d], 1);
    csrc[rowp[d] + p] = src[e];
  }
}

// ---------------- shared GEMM tile machinery (64x64 C-tile, 256 thr, 4x4/thr) ----------------
__device__ __forceinline__ void load_A_tile(const float* __restrict__ A, int row0, int lda, int kcol0, float* As){
  int t = threadIdx.x;
  int lr = t>>2;             // row 0..63
  int lc = (t&3)*16;         // k base 0/16/32/48
  float4 a0,a1,a2,a3;
  int row = row0 + lr;
  if(row < NN){
    const float* ap = A + (size_t)row*lda + kcol0 + lc;
    a0=*(const float4*)ap; a1=*(const float4*)(ap+4); a2=*(const float4*)(ap+8); a3=*(const float4*)(ap+12);
  } else {
    a0=a1=a2=a3=make_float4(0.f,0.f,0.f,0.f);
  }
  float* d = As + (size_t)lc*68 + lr;
  d[0*68]=a0.x;  d[1*68]=a0.y;  d[2*68]=a0.z;  d[3*68]=a0.w;
  d[4*68]=a1.x;  d[5*68]=a1.y;  d[6*68]=a1.z;  d[7*68]=a1.w;
  d[8*68]=a2.x;  d[9*68]=a2.y;  d[10*68]=a2.z; d[11*68]=a2.w;
  d[12*68]=a3.x; d[13*68]=a3.y; d[14*68]=a3.z; d[15*68]=a3.w;
}

__device__ __forceinline__ void load_B_tile(const float* __restrict__ B, int krow0, float* Bs){
  int t = threadIdx.x;
  int bk = t>>2; int lc = (t&3)*16;
  const float* bp = B + (size_t)(krow0+bk)*64 + lc;
  *(float4*)(Bs + bk*64 + lc)      = *(const float4*)bp;
  *(float4*)(Bs + bk*64 + lc + 4)  = *(const float4*)(bp+4);
  *(float4*)(Bs + bk*64 + lc + 8)  = *(const float4*)(bp+8);
  *(float4*)(Bs + bk*64 + lc + 12) = *(const float4*)(bp+12);
}

// partial unroll: keeps live set ~60 VGPR
__device__ __forceinline__ void tile64_compute(const float* __restrict__ As, const float* __restrict__ Bs,
                                               float acc[4][4], int ty, int tx){
  #pragma unroll 4
  for(int kk=0; kk<64; kk++){
    float4 a = *(const float4*)(As + kk*68 + ty*4);
    float4 b = *(const float4*)(Bs + kk*64 + tx*4);
    acc[0][0]+=a.x*b.x; acc[0][1]+=a.x*b.y; acc[0][2]+=a.x*b.z; acc[0][3]+=a.x*b.w;
    acc[1][0]+=a.y*b.x; acc[1][1]+=a.y*b.y; acc[1][2]+=a.y*b.z; acc[1][3]+=a.y*b.w;
    acc[2][0]+=a.z*b.x; acc[2][1]+=a.z*b.y; acc[2][2]+=a.z*b.z; acc[2][3]+=a.z*b.w;
    acc[3][0]+=a.w*b.x; acc[3][1]+=a.w*b.y; acc[3][2]+=a.w*b.z; acc[3][3]+=a.w*b.w;
  }
}

// proj_feat = ft @ Wp   [NN,512]@[512,64]
__global__ __launch_bounds__(256, 4) void k_gemm_proj(const float* __restrict__ A, const float* __restrict__ B, float* __restrict__ C){
  __shared__ float As[64*68];
  __shared__ float Bs[64*64];
  int row0 = blockIdx.x*64;
  int ty = threadIdx.x>>4, tx = threadIdx.x&15;
  float acc[4][4] = {};
  #pragma unroll 1
  for(int kt=0; kt<IND; kt+=64){
    __syncthreads();
    load_A_tile(A, row0, IND, kt, As);
    load_B_tile(B, kt, Bs);
    __syncthreads();
    tile64_compute(As, Bs, acc, ty, tx);
  }
  #pragma unroll
  for(int i=0;i<4;i++){
    int row = row0 + ty*4 + i;
    if(row < NN) *(float4*)(C + (size_t)row*64 + tx*4) = make_float4(acc[i][0],acc[i][1],acc[i][2],acc[i][3]);
  }
}

// node matmuls merged: proj_z = cur@We AND pooled = cur@Wg
__global__ __launch_bounds__(256, 4) void k_nodemm2(const float* __restrict__ cur, const float* __restrict__ We,
                                                    const float* __restrict__ Wg,
                                                    float* __restrict__ projz, float* __restrict__ pooled){
  __shared__ float As[64*68];
  __shared__ float Bs[64*64];
  int row0 = blockIdx.x*64;
  int ty = threadIdx.x>>4, tx = threadIdx.x&15;
  load_A_tile(cur, row0, 64, 0, As);
  #pragma unroll 1
  for(int bi=0; bi<2; ++bi){
    const float* B = bi ? Wg : We;
    float* C = bi ? pooled : projz;
    __syncthreads();
    load_B_tile(B, 0, Bs);
    __syncthreads();
    float acc[4][4] = {};
    tile64_compute(As, Bs, acc, ty, tx);
    #pragma unroll
    for(int i=0;i<4;i++){
      int row = row0 + ty*4 + i;
      if(row < NN) *(float4*)(C + (size_t)row*64 + tx*4) = make_float4(acc[i][0],acc[i][1],acc[i][2],acc[i][3]);
    }
  }
}

// el/er per node per head (wave per node, butterfly reduce)
__global__ __launch_bounds__(256) void k_eler(const float* __restrict__ projz, const float* __restrict__ al,
                                              const float* __restrict__ ar, float* __restrict__ el, float* __restrict__ er){
  int wid = threadIdx.x>>6, lane = threadIdx.x&63;
  int n = blockIdx.x*4 + wid;
  if(n >= NN) return;
  float z = projz[(size_t)n*64 + lane];
  #pragma unroll
  for(int h=0; h<4; h++){
    float pl = z*al[h*64+lane];
    float pr = z*ar[h*64+lane];
    #pragma unroll
    for(int st=32; st; st>>=1){ pl += __shfl_xor(pl, st, 64); pr += __shfl_xor(pr, st, 64); }
    if(lane==0){ el[(size_t)n*4+h]=pl; er[(size_t)n*4+h]=pr; }
  }
}

// per-node edge kernel, chunked: lanes compute per-edge exp in parallel, stage {s,x} in
// per-wave LDS, then a uniform j-loop does the dim-parallel accumulation.
// No max subtraction: logits = lrelu(el+er) are O(1..8); softmax is shift-invariant,
// exp stays far inside fp32 range. den accumulated per-lane, butterfly-reduced at end.
__global__ __launch_bounds__(256) void k_edge(const int* __restrict__ rowp, const int* __restrict__ csrc,
    const float* __restrict__ el, const float* __restrict__ er, const float* __restrict__ cur,
    const float* __restrict__ pooled,
    const float* __restrict__ Wg, const float* __restrict__ bg, float* __restrict__ aggcg)
{
  __shared__ int    ssh[4][64];
  __shared__ float4 xsh[4][64];
  int wid = threadIdx.x>>6, lane = threadIdx.x&63;
  int d = blockIdx.x*4 + wid;
  if(d >= NN) return;
  int e0 = rowp[d], e1 = rowp[d+1];
  float4 erd = *(const float4*)(er + (size_t)d*4);
  float n0=0,n1=0,n2=0,n3=0, den0=0,den1=0,den2=0,den3=0, mn=0, mxp=-1e30f;

  for(int c=e0; c<e1; c+=64){
    int jmax = min(64, e1-c);
    // lane-parallel: each lane handles one edge of the chunk
    float x0=0.f, x1=0.f, x2=0.f, x3=0.f; int s=0;
    if(lane < jmax){
      s = csrc[c+lane];
      float4 ev = *(const float4*)(el + (size_t)s*4);
      x0 = __expf(lrelu(ev.x+erd.x, 0.2f));
      x1 = __expf(lrelu(ev.y+erd.y, 0.2f));
      x2 = __expf(lrelu(ev.z+erd.z, 0.2f));
      x3 = __expf(lrelu(ev.w+erd.w, 0.2f));
      den0+=x0; den1+=x1; den2+=x2; den3+=x3;
    }
    ssh[wid][lane] = s;
    xsh[wid][lane] = make_float4(x0,x1,x2,x3);
    // uniform accumulation: lanes over the 64 feature dims
    for(int j=0; j<jmax; ++j){
      int sj = __builtin_amdgcn_readfirstlane(ssh[wid][j]);   // SGPR base -> SALU addr math
      float4 xj = xsh[wid][j];                                 // broadcast read
      const float* cp = cur    + (size_t)sj*64;
      const float* pp = pooled + (size_t)sj*64;
      float cv = cp[lane];
      float pv = pp[lane];
      n0 += xj.x*cv; n1 += xj.y*cv; n2 += xj.z*cv; n3 += xj.w*cv;
      mn += cv;
      mxp = fmaxf(mxp, pv);
    }
  }
  // all-lanes den via butterfly
  #pragma unroll
  for(int st=32; st; st>>=1){
    den0+=__shfl_xor(den0,st,64); den1+=__shfl_xor(den1,st,64);
    den2+=__shfl_xor(den2,st,64); den3+=__shfl_xor(den3,st,64);
  }
  // GaAN gate
  float cd  = cur[(size_t)d*64 + lane];
  float mnn = mn / (float)(e1-e0);
  float4 w0 = *(const float4*)(Wg + lane*4);
  float4 w1 = *(const float4*)(Wg + (64+lane)*4);
  float4 w2 = *(const float4*)(Wg + (128+lane)*4);
  float g0 = cd*w0.x + mxp*w1.x + mnn*w2.x;
  float g1 = cd*w0.y + mxp*w1.y + mnn*w2.y;
  float g2 = cd*w0.z + mxp*w1.z + mnn*w2.z;
  float g3 = cd*w0.w + mxp*w1.w + mnn*w2.w;
  #pragma unroll
  for(int st=32; st; st>>=1){
    g0+=__shfl_xor(g0,st,64); g1+=__shfl_xor(g1,st,64);
    g2+=__shfl_xor(g2,st,64); g3+=__shfl_xor(g3,st,64);
  }
  g0 = 1.f/(1.f+__expf(-(g0+bg[0])));
  g1 = 1.f/(1.f+__expf(-(g1+bg[1])));
  g2 = 1.f/(1.f+__expf(-(g2+bg[2])));
  g3 = 1.f/(1.f+__expf(-(g3+bg[3])));
  float* od = aggcg + (size_t)d*256;
  od[lane]       = g0 * n0/den0;
  od[64 + lane]  = g1 * n1/den1;
  od[128 + lane] = g2 * n2/den2;
  od[192 + lane] = g3 * n3/den3;
}

// layer0 post: cur1 = lrelu(0.25 * aggcg[N,256] @ WvStack[256,64])
__global__ __launch_bounds__(256, 4) void k_post0(const float* __restrict__ A, const float* __restrict__ B, float* __restrict__ C){
  __shared__ float As[64*68];
  __shared__ float Bs[64*64];
  int row0 = blockIdx.x*64;
  int ty = threadIdx.x>>4, tx = threadIdx.x&15;
  float acc[4][4] = {};
  #pragma unroll 1
  for(int kt=0; kt<256; kt+=64){
    __syncthreads();
    load_A_tile(A, row0, 256, kt, As);
    load_B_tile(B, kt, Bs);
    __syncthreads();
    tile64_compute(As, Bs, acc, ty, tx);
  }
  #pragma unroll
  for(int i=0;i<4;i++){
    int row = row0 + ty*4 + i;
    if(row < NN) *(float4*)(C + (size_t)row*64 + tx*4) =
      make_float4(lrelu(0.25f*acc[i][0],0.01f), lrelu(0.25f*acc[i][1],0.01f),
                  lrelu(0.25f*acc[i][2],0.01f), lrelu(0.25f*acc[i][3],0.01f));
  }
}

// layer1 post: cur2[:, h*64:(h+1)*64] = lrelu(aggcg[:, h*64:]@Wv1[h]) — looped over heads
__global__ __launch_bounds__(256, 4) void k_post1(const float* __restrict__ aggcg, const float* __restrict__ Wv1, float* __restrict__ cur2){
  __shared__ float As[64*68];
  __shared__ float Bs[64*64];
  int row0 = blockIdx.x*64;
  int ty = threadIdx.x>>4, tx = threadIdx.x&15;
  #pragma unroll 1
  for(int h=0; h<4; ++h){
    __syncthreads();
    load_A_tile(aggcg + h*64, row0, 256, 0, As);
    load_B_tile(Wv1 + (size_t)h*4096, 0, Bs);
    __syncthreads();
    float acc[4][4] = {};
    tile64_compute(As, Bs, acc, ty, tx);
    #pragma unroll
    for(int i=0;i<4;i++){
      int row = row0 + ty*4 + i;
      if(row < NN) *(float4*)(cur2 + (size_t)row*256 + h*64 + tx*4) =
        make_float4(lrelu(acc[i][0],0.01f), lrelu(acc[i][1],0.01f),
                    lrelu(acc[i][2],0.01f), lrelu(acc[i][3],0.01f));
    }
  }
}

// out = concat(proj_feat, cur2) @ Wtran + btran   (K=320)
__global__ __launch_bounds__(256, 4) void k_final(const float* __restrict__ pf, const float* __restrict__ cur2,
                                                  const float* __restrict__ Wt, const float* __restrict__ bt,
                                                  float* __restrict__ C){
  __shared__ float As[64*68];
  __shared__ float Bs[64*64];
  int row0 = blockIdx.x*64;
  int ty = threadIdx.x>>4, tx = threadIdx.x&15;
  float acc[4][4] = {};
  #pragma unroll 1
  for(int kt=0; kt<320; kt+=64){
    __syncthreads();
    if(kt==0) load_A_tile(pf, row0, 64, 0, As);
    else      load_A_tile(cur2, row0, 256, kt-64, As);
    load_B_tile(Wt, kt, Bs);
    __syncthreads();
    tile64_compute(As, Bs, acc, ty, tx);
  }
  float4 bias = *(const float4*)(bt + tx*4);
  #pragma unroll
  for(int i=0;i<4;i++){
    int row = row0 + ty*4 + i;
    if(row < NN){
      *(float4*)(C + (size_t)row*64 + tx*4) =
        make_float4(acc[i][0]+bias.x, acc[i][1]+bias.y, acc[i][2]+bias.z, acc[i][3]+bias.w);
    }
  }
}

extern "C" void kernel_launch(void* const* d_in, const int* in_sizes, int n_in,
                              void* d_out, int out_size, void* d_ws, size_t ws_size,
                              hipStream_t stream) {
  const float* ft    = (const float*)d_in[0];
  const float* Wp    = (const float*)d_in[1];
  const float* We    = (const float*)d_in[2];
  const float* a_l   = (const float*)d_in[3];
  const float* a_r   = (const float*)d_in[4];
  const float* Wv    = (const float*)d_in[5];
  const float* Wgp   = (const float*)d_in[6];
  const float* Wgate = (const float*)d_in[7];
  const float* bgate = (const float*)d_in[8];
  const float* Wtran = (const float*)d_in[9];
  const float* btran = (const float*)d_in[10];
  const int*   src   = (const int*)d_in[11];
  const int*   dst   = (const int*)d_in[12];
  float* out = (float*)d_out;

  char* p = (char*)d_ws;
  auto alloc = [&](size_t bytes)->char* { char* r = p; p += (bytes + 255) & ~(size_t)255; return r; };
  int* deg  = (int*)alloc((size_t)NN*4);
  int* cnt  = (int*)alloc((size_t)NN*4);
  int* rowp = (int*)alloc((size_t)(NN+1)*4);
  int* psum = (int*)alloc(64*4);
  int* csrc = (int*)alloc((size_t)EE*4);
  float* pf    = (float*)alloc((size_t)NN*64*4);
  float* cur1  = (float*)alloc((size_t)NN*64*4);
  float* cur2  = (float*)alloc((size_t)NN*256*4);
  float* elb   = (float*)alloc((size_t)NN*4*4);
  float* erb   = (float*)alloc((size_t)NN*4*4);
  float* pz    = (float*)alloc((size_t)NN*64*4);
  float* pool  = (float*)alloc((size_t)NN*64*4);
  float* aggcg = (float*)alloc((size_t)NN*256*4);

  hipMemsetAsync(deg, 0, (size_t)NN*4, stream);
  hipMemsetAsync(cnt, 0, (size_t)NN*4, stream);
  k_deg<<<(EE+255)/256, 256, 0, stream>>>(dst, deg);
  k_scan1<<<NB_SCAN, 256, 0, stream>>>(deg, psum);
  k_scan2<<<1, 64, 0, stream>>>(psum, NB_SCAN);
  k_scan3<<<NB_SCAN, 256, 0, stream>>>(deg, psum, rowp);
  k_fill<<<(EE+255)/256, 256, 0, stream>>>(src, dst, rowp, cnt, csrc);

  k_gemm_proj<<<(NN+63)/64, 256, 0, stream>>>(ft, Wp, pf);

  int gb = (NN+63)/64;
  // layer 0 (cur = proj_feat)
  k_nodemm2<<<gb, 256, 0, stream>>>(pf, We, Wgp, pz, pool);
  k_eler<<<NN/4, 256, 0, stream>>>(pz, a_l, a_r, elb, erb);
  k_edge<<<NN/4, 256, 0, stream>>>(rowp, csrc, elb, erb, pf, pool, Wgate, bgate, aggcg);
  k_post0<<<gb, 256, 0, stream>>>(aggcg, Wv, cur1);
  // layer 1
  k_nodemm2<<<gb, 256, 0, stream>>>(cur1, We, Wgp + 4096, pz, pool);
  k_eler<<<NN/4, 256, 0, stream>>>(pz, a_l + 256, a_r + 256, elb, erb);
  k_edge<<<NN/4, 256, 0, stream>>>(rowp, csrc, elb, erb, cur1, pool, Wgate + 768, bgate + 4, aggcg);
  k_post1<<<gb, 256, 0, stream>>>(aggcg, Wv + 16384, cur2);

  k_final<<<gb, 256, 0, stream>>>(pf, cur2, Wtran, btran, out);
}

// Round 6
// 632.404 us; speedup vs baseline: 2.1128x; 1.0203x over previous
//
#include <hip/hip_runtime.h>
#include <hip/hip_fp16.h>

#define NN 50000
#define EE 800000      // 750000 random + 50000 self-loops
#define IND 512
#define HD 64
#define NB_SCAN 49     // ceil(NN/1024)

__device__ __forceinline__ float lrelu(float x, float s){ return x > 0.f ? x : s*x; }

// ---------------- CSR build (by dst) ----------------
__global__ void k_deg(const int* __restrict__ dst, int* __restrict__ deg){
  int e = blockIdx.x*256 + threadIdx.x;
  if(e < EE) atomicAdd(&deg[dst[e]], 1);
}

__global__ void k_scan1(const int* __restrict__ deg, int* __restrict__ psum){
  __shared__ int sh[256];
  int base = blockIdx.x*1024 + threadIdx.x*4;
  int s = 0;
  #pragma unroll
  for(int j=0;j<4;j++){ int i=base+j; if(i<NN) s += deg[i]; }
  sh[threadIdx.x]=s; __syncthreads();
  for(int st=128; st>0; st>>=1){ if(threadIdx.x<st) sh[threadIdx.x]+=sh[threadIdx.x+st]; __syncthreads(); }
  if(threadIdx.x==0) psum[blockIdx.x]=sh[0];
}

__global__ void k_scan2(int* __restrict__ psum, int nb){
  if(threadIdx.x==0){ int acc=0; for(int i=0;i<nb;i++){ int v=psum[i]; psum[i]=acc; acc+=v; } psum[nb]=acc; }
}

__global__ void k_scan3(const int* __restrict__ deg, const int* __restrict__ psum, int* __restrict__ rowp){
  __shared__ int sh[256];
  int t = threadIdx.x;
  int base = blockIdx.x*1024 + t*4;
  int v[4]; int s=0;
  #pragma unroll
  for(int j=0;j<4;j++){ int i=base+j; v[j] = (i<NN)?deg[i]:0; s+=v[j]; }
  sh[t]=s; __syncthreads();
  for(int st=1; st<256; st<<=1){
    int add = (t>=st)? sh[t-st] : 0;
    __syncthreads();
    sh[t] += add;
    __syncthreads();
  }
  int excl = sh[t]-s + psum[blockIdx.x];
  #pragma unroll
  for(int j=0;j<4;j++){ int i=base+j; if(i<NN){ rowp[i]=excl; excl+=v[j]; } }
  if(blockIdx.x==0 && t==0) rowp[NN] = psum[NB_SCAN];
}

__global__ void k_fill(const int* __restrict__ src, const int* __restrict__ dst,
                       const int* __restrict__ rowp, int* __restrict__ cnt, int* __restrict__ csrc){
  int e = blockIdx.x*256 + threadIdx.x;
  if(e < EE){
    int d = dst[e];
    int p = atomicAdd(&cnt[d], 1);
    csrc[rowp[d] + p] = src[e];
  }
}

// w_elr[layer][o][k]: o<4 -> el head o, o>=4 -> er head o-4.  w_el[k,h] = dot(We[k,:], a_l[h,:])
__global__ void k_prew(const float* __restrict__ We, const float* __restrict__ al,
                       const float* __restrict__ ar, float* __restrict__ w_elr){
  int t = blockIdx.x*256 + threadIdx.x;
  if(t >= 1024) return;
  int layer = t>>9, o = (t>>6)&7, k = t&63;
  const float* a = (o<4 ? al : ar) + layer*256 + (o&3)*64;
  const float* w = We + k*64;
  float s = 0.f;
  for(int d2=0; d2<64; ++d2) s += w[d2]*a[d2];
  w_elr[t] = s;
}

// ---------------- shared GEMM tile machinery (64x64 C-tile, 256 thr, 4x4/thr) ----------------
__device__ __forceinline__ void load_A_tile(const float* __restrict__ A, int row0, int lda, int kcol0, float* As){
  int t = threadIdx.x;
  int lr = t>>2;             // row 0..63
  int lc = (t&3)*16;         // k base 0/16/32/48
  float4 a0,a1,a2,a3;
  int row = row0 + lr;
  if(row < NN){
    const float* ap = A + (size_t)row*lda + kcol0 + lc;
    a0=*(const float4*)ap; a1=*(const float4*)(ap+4); a2=*(const float4*)(ap+8); a3=*(const float4*)(ap+12);
  } else {
    a0=a1=a2=a3=make_float4(0.f,0.f,0.f,0.f);
  }
  float* d = As + (size_t)lc*68 + lr;
  d[0*68]=a0.x;  d[1*68]=a0.y;  d[2*68]=a0.z;  d[3*68]=a0.w;
  d[4*68]=a1.x;  d[5*68]=a1.y;  d[6*68]=a1.z;  d[7*68]=a1.w;
  d[8*68]=a2.x;  d[9*68]=a2.y;  d[10*68]=a2.z; d[11*68]=a2.w;
  d[12*68]=a3.x; d[13*68]=a3.y; d[14*68]=a3.z; d[15*68]=a3.w;
}

__device__ __forceinline__ void load_B_tile(const float* __restrict__ B, int krow0, float* Bs){
  int t = threadIdx.x;
  int bk = t>>2; int lc = (t&3)*16;
  const float* bp = B + (size_t)(krow0+bk)*64 + lc;
  *(float4*)(Bs + bk*64 + lc)      = *(const float4*)bp;
  *(float4*)(Bs + bk*64 + lc + 4)  = *(const float4*)(bp+4);
  *(float4*)(Bs + bk*64 + lc + 8)  = *(const float4*)(bp+8);
  *(float4*)(Bs + bk*64 + lc + 12) = *(const float4*)(bp+12);
}

__device__ __forceinline__ void tile64_compute(const float* __restrict__ As, const float* __restrict__ Bs,
                                               float acc[4][4], int ty, int tx){
  #pragma unroll 4
  for(int kk=0; kk<64; kk++){
    float4 a = *(const float4*)(As + kk*68 + ty*4);
    float4 b = *(const float4*)(Bs + kk*64 + tx*4);
    acc[0][0]+=a.x*b.x; acc[0][1]+=a.x*b.y; acc[0][2]+=a.x*b.z; acc[0][3]+=a.x*b.w;
    acc[1][0]+=a.y*b.x; acc[1][1]+=a.y*b.y; acc[1][2]+=a.y*b.z; acc[1][3]+=a.y*b.w;
    acc[2][0]+=a.z*b.x; acc[2][1]+=a.z*b.y; acc[2][2]+=a.z*b.z; acc[2][3]+=a.z*b.w;
    acc[3][0]+=a.w*b.x; acc[3][1]+=a.w*b.y; acc[3][2]+=a.w*b.z; acc[3][3]+=a.w*b.w;
  }
}

// proj_feat = ft @ Wp   [NN,512]@[512,64]
__global__ __launch_bounds__(256, 4) void k_gemm_proj(const float* __restrict__ A, const float* __restrict__ B, float* __restrict__ C){
  __shared__ float As[64*68];
  __shared__ float Bs[64*64];
  int row0 = blockIdx.x*64;
  int ty = threadIdx.x>>4, tx = threadIdx.x&15;
  float acc[4][4] = {};
  #pragma unroll 1
  for(int kt=0; kt<IND; kt+=64){
    __syncthreads();
    load_A_tile(A, row0, IND, kt, As);
    load_B_tile(B, kt, Bs);
    __syncthreads();
    tile64_compute(As, Bs, acc, ty, tx);
  }
  #pragma unroll
  for(int i=0;i<4;i++){
    int row = row0 + ty*4 + i;
    if(row < NN) *(float4*)(C + (size_t)row*64 + tx*4) = make_float4(acc[i][0],acc[i][1],acc[i][2],acc[i][3]);
  }
}

// pooled = cur @ Wg, then pack {cur, pooled} rows as half2[N][64] (cur tile read back from As)
__global__ __launch_bounds__(256, 4) void k_nodemm_pack(const float* __restrict__ cur, const float* __restrict__ Wg,
                                                        __half2* __restrict__ pack){
  __shared__ float As[64*68];
  __shared__ float Bs[64*64];
  int row0 = blockIdx.x*64;
  int ty = threadIdx.x>>4, tx = threadIdx.x&15;
  load_A_tile(cur, row0, 64, 0, As);
  load_B_tile(Wg, 0, Bs);
  __syncthreads();
  float acc[4][4] = {};
  tile64_compute(As, Bs, acc, ty, tx);
  #pragma unroll
  for(int i=0;i<4;i++){
    int row = row0 + ty*4 + i;
    if(row < NN){
      union { uint4 u; __half2 h[4]; } pk;
      #pragma unroll
      for(int j=0;j<4;j++){
        float cv = As[(tx*4+j)*68 + ty*4 + i];
        pk.h[j] = __floats2half2_rn(cv, acc[i][j]);
      }
      *(uint4*)(pack + (size_t)row*64 + tx*4) = pk.u;
    }
  }
}

// el/er per node via folded weights: el[n,h] = dot(cur[n,:], w_elr[h,:])
__global__ __launch_bounds__(256) void k_eler2(const float* __restrict__ cur, const float* __restrict__ w_elr,
                                               float* __restrict__ el, float* __restrict__ er){
  int wid = threadIdx.x>>6, lane = threadIdx.x&63;
  int n = blockIdx.x*4 + wid;
  if(n >= NN) return;
  float c = cur[(size_t)n*64 + lane];
  #pragma unroll
  for(int o=0; o<8; o++){
    float p = c * w_elr[o*64 + lane];
    #pragma unroll
    for(int st=32; st; st>>=1) p += __shfl_xor(p, st, 64);
    if(lane==0){
      if(o<4) el[(size_t)n*4 + o] = p;
      else    er[(size_t)n*4 + o-4] = p;
    }
  }
}

// per-node edge kernel: lane-parallel exp -> LDS, then uniform j-loop gathers one half2 stream
__global__ __launch_bounds__(256) void k_edge(const int* __restrict__ rowp, const int* __restrict__ csrc,
    const float* __restrict__ el, const float* __restrict__ er, const float* __restrict__ cur,
    const __half2* __restrict__ pack,
    const float* __restrict__ Wg, const float* __restrict__ bg, float* __restrict__ aggcg)
{
  __shared__ int    ssh[4][64];
  __shared__ float4 xsh[4][64];
  int wid = threadIdx.x>>6, lane = threadIdx.x&63;
  int d = blockIdx.x*4 + wid;
  if(d >= NN) return;
  int e0 = rowp[d], e1 = rowp[d+1];
  float4 erd = *(const float4*)(er + (size_t)d*4);
  float n0=0,n1=0,n2=0,n3=0, den0=0,den1=0,den2=0,den3=0, mn=0, mxp=-1e30f;

  for(int c=e0; c<e1; c+=64){
    int jmax = min(64, e1-c);
    float x0=0.f, x1=0.f, x2=0.f, x3=0.f; int s=0;
    if(lane < jmax){
      s = csrc[c+lane];
      float4 ev = *(const float4*)(el + (size_t)s*4);
      x0 = __expf(lrelu(ev.x+erd.x, 0.2f));
      x1 = __expf(lrelu(ev.y+erd.y, 0.2f));
      x2 = __expf(lrelu(ev.z+erd.z, 0.2f));
      x3 = __expf(lrelu(ev.w+erd.w, 0.2f));
      den0+=x0; den1+=x1; den2+=x2; den3+=x3;
    }
    ssh[wid][lane] = s;
    xsh[wid][lane] = make_float4(x0,x1,x2,x3);
    for(int j=0; j<jmax; ++j){
      int sj = __builtin_amdgcn_readfirstlane(ssh[wid][j]);
      float4 xj = xsh[wid][j];
      float2 f = __half22float2(pack[(size_t)sj*64 + lane]);   // {cur, pooled}
      n0 += xj.x*f.x; n1 += xj.y*f.x; n2 += xj.z*f.x; n3 += xj.w*f.x;
      mn += f.x;
      mxp = fmaxf(mxp, f.y);
    }
  }
  #pragma unroll
  for(int st=32; st; st>>=1){
    den0+=__shfl_xor(den0,st,64); den1+=__shfl_xor(den1,st,64);
    den2+=__shfl_xor(den2,st,64); den3+=__shfl_xor(den3,st,64);
  }
  // GaAN gate (cd in fp32)
  float cd  = cur[(size_t)d*64 + lane];
  float mnn = mn / (float)(e1-e0);
  float4 w0 = *(const float4*)(Wg + lane*4);
  float4 w1 = *(const float4*)(Wg + (64+lane)*4);
  float4 w2 = *(const float4*)(Wg + (128+lane)*4);
  float g0 = cd*w0.x + mxp*w1.x + mnn*w2.x;
  float g1 = cd*w0.y + mxp*w1.y + mnn*w2.y;
  float g2 = cd*w0.z + mxp*w1.z + mnn*w2.z;
  float g3 = cd*w0.w + mxp*w1.w + mnn*w2.w;
  #pragma unroll
  for(int st=32; st; st>>=1){
    g0+=__shfl_xor(g0,st,64); g1+=__shfl_xor(g1,st,64);
    g2+=__shfl_xor(g2,st,64); g3+=__shfl_xor(g3,st,64);
  }
  g0 = 1.f/(1.f+__expf(-(g0+bg[0])));
  g1 = 1.f/(1.f+__expf(-(g1+bg[1])));
  g2 = 1.f/(1.f+__expf(-(g2+bg[2])));
  g3 = 1.f/(1.f+__expf(-(g3+bg[3])));
  float* od = aggcg + (size_t)d*256;
  od[lane]       = g0 * n0/den0;
  od[64 + lane]  = g1 * n1/den1;
  od[128 + lane] = g2 * n2/den2;
  od[192 + lane] = g3 * n3/den3;
}

// layer0 post: cur1 = lrelu(0.25 * aggcg[N,256] @ WvStack[256,64])
__global__ __launch_bounds__(256, 4) void k_post0(const float* __restrict__ A, const float* __restrict__ B, float* __restrict__ C){
  __shared__ float As[64*68];
  __shared__ float Bs[64*64];
  int row0 = blockIdx.x*64;
  int ty = threadIdx.x>>4, tx = threadIdx.x&15;
  float acc[4][4] = {};
  #pragma unroll 1
  for(int kt=0; kt<256; kt+=64){
    __syncthreads();
    load_A_tile(A, row0, 256, kt, As);
    load_B_tile(B, kt, Bs);
    __syncthreads();
    tile64_compute(As, Bs, acc, ty, tx);
  }
  #pragma unroll
  for(int i=0;i<4;i++){
    int row = row0 + ty*4 + i;
    if(row < NN) *(float4*)(C + (size_t)row*64 + tx*4) =
      make_float4(lrelu(0.25f*acc[i][0],0.01f), lrelu(0.25f*acc[i][1],0.01f),
                  lrelu(0.25f*acc[i][2],0.01f), lrelu(0.25f*acc[i][3],0.01f));
  }
}

// fused layer1-post + final: out = [pf, lrelu(aggcg_h @ Wv1_h)_h] @ Wtran + btran
__global__ __launch_bounds__(256, 4) void k_final2(const float* __restrict__ pf, const float* __restrict__ aggcg,
                                                   const float* __restrict__ Wv1, const float* __restrict__ Wt,
                                                   const float* __restrict__ bt, float* __restrict__ C){
  __shared__ float As[64*68];
  __shared__ float Bs[64*64];
  int row0 = blockIdx.x*64;
  int ty = threadIdx.x>>4, tx = threadIdx.x&15;
  float accF[4][4] = {};
  // K-block 0: pf @ Wt[0:64]
  load_A_tile(pf, row0, 64, 0, As);
  load_B_tile(Wt, 0, Bs);
  __syncthreads();
  tile64_compute(As, Bs, accF, ty, tx);
  // K-blocks 1..4: cur2_h = lrelu(aggcg_h @ Wv1_h); accF += cur2_h @ Wt[64+h*64 : ...]
  #pragma unroll 1
  for(int h=0; h<4; ++h){
    __syncthreads();                          // done with As/Bs
    load_A_tile(aggcg + h*64, row0, 256, 0, As);
    load_B_tile(Wv1 + (size_t)h*4096, 0, Bs);
    __syncthreads();
    float acc1[4][4] = {};
    tile64_compute(As, Bs, acc1, ty, tx);
    __syncthreads();                          // done reading As/Bs
    #pragma unroll
    for(int i=0;i<4;i++)
      #pragma unroll
      for(int j=0;j<4;j++)
        As[(tx*4+j)*68 + ty*4 + i] = lrelu(acc1[i][j], 0.01f);   // cur2_h tile, A-layout
    load_B_tile(Wt, 64 + h*64, Bs);
    __syncthreads();
    tile64_compute(As, Bs, accF, ty, tx);
  }
  float4 bias = *(const float4*)(bt + tx*4);
  #pragma unroll
  for(int i=0;i<4;i++){
    int row = row0 + ty*4 + i;
    if(row < NN){
      *(float4*)(C + (size_t)row*64 + tx*4) =
        make_float4(accF[i][0]+bias.x, accF[i][1]+bias.y, accF[i][2]+bias.z, accF[i][3]+bias.w);
    }
  }
}

extern "C" void kernel_launch(void* const* d_in, const int* in_sizes, int n_in,
                              void* d_out, int out_size, void* d_ws, size_t ws_size,
                              hipStream_t stream) {
  const float* ft    = (const float*)d_in[0];
  const float* Wp    = (const float*)d_in[1];
  const float* We    = (const float*)d_in[2];
  const float* a_l   = (const float*)d_in[3];
  const float* a_r   = (const float*)d_in[4];
  const float* Wv    = (const float*)d_in[5];
  const float* Wgp   = (const float*)d_in[6];
  const float* Wgate = (const float*)d_in[7];
  const float* bgate = (const float*)d_in[8];
  const float* Wtran = (const float*)d_in[9];
  const float* btran = (const float*)d_in[10];
  const int*   src   = (const int*)d_in[11];
  const int*   dst   = (const int*)d_in[12];
  float* out = (float*)d_out;

  char* p = (char*)d_ws;
  auto alloc = [&](size_t bytes)->char* { char* r = p; p += (bytes + 255) & ~(size_t)255; return r; };
  int* deg  = (int*)alloc((size_t)NN*4);
  int* cnt  = (int*)alloc((size_t)NN*4);
  int* rowp = (int*)alloc((size_t)(NN+1)*4);
  int* psum = (int*)alloc(64*4);
  int* csrc = (int*)alloc((size_t)EE*4);
  float*   pf    = (float*)alloc((size_t)NN*64*4);
  float*   cur1  = (float*)alloc((size_t)NN*64*4);
  float*   elb   = (float*)alloc((size_t)NN*4*4);
  float*   erb   = (float*)alloc((size_t)NN*4*4);
  __half2* pack  = (__half2*)alloc((size_t)NN*64*4);
  float*   aggcg = (float*)alloc((size_t)NN*256*4);
  float*   welr  = (float*)alloc(1024*4);

  hipMemsetAsync(deg, 0, (size_t)NN*4, stream);
  hipMemsetAsync(cnt, 0, (size_t)NN*4, stream);
  k_deg<<<(EE+255)/256, 256, 0, stream>>>(dst, deg);
  k_scan1<<<NB_SCAN, 256, 0, stream>>>(deg, psum);
  k_scan2<<<1, 64, 0, stream>>>(psum, NB_SCAN);
  k_scan3<<<NB_SCAN, 256, 0, stream>>>(deg, psum, rowp);
  k_fill<<<(EE+255)/256, 256, 0, stream>>>(src, dst, rowp, cnt, csrc);
  k_prew<<<4, 256, 0, stream>>>(We, a_l, a_r, welr);

  k_gemm_proj<<<(NN+63)/64, 256, 0, stream>>>(ft, Wp, pf);

  int gb = (NN+63)/64;
  // layer 0 (cur = pf)
  k_nodemm_pack<<<gb, 256, 0, stream>>>(pf, Wgp, pack);
  k_eler2<<<NN/4, 256, 0, stream>>>(pf, welr, elb, erb);
  k_edge<<<NN/4, 256, 0, stream>>>(rowp, csrc, elb, erb, pf, pack, Wgate, bgate, aggcg);
  k_post0<<<gb, 256, 0, stream>>>(aggcg, Wv, cur1);
  // layer 1 (cur = cur1)
  k_nodemm_pack<<<gb, 256, 0, stream>>>(cur1, Wgp + 4096, pack);
  k_eler2<<<NN/4, 256, 0, stream>>>(cur1, welr + 512, elb, erb);
  k_edge<<<NN/4, 256, 0, stream>>>(rowp, csrc, elb, erb, cur1, pack, Wgate + 768, bgate + 4, aggcg);
  // fused layer1-post + final transform
  k_final2<<<gb, 256, 0, stream>>>(pf, aggcg, Wv + 16384, Wtran, btran, out);
}

// Round 7
// 564.529 us; speedup vs baseline: 2.3668x; 1.1202x over previous
//
#include <hip/hip_runtime.h>
#include <hip/hip_fp16.h>

#define NN 50000
#define EE 800000      // 750000 random + 50000 self-loops
#define IND 512
#define HD 64
#define NB_SCAN 49     // ceil(NN/1024)

__device__ __forceinline__ float lrelu(float x, float s){ return x > 0.f ? x : s*x; }

// ---------------- CSR build (by dst) ----------------
__global__ void k_deg(const int* __restrict__ dst, int* __restrict__ deg){
  int e = blockIdx.x*256 + threadIdx.x;
  if(e < EE) atomicAdd(&deg[dst[e]], 1);
}

__global__ void k_scan1(const int* __restrict__ deg, int* __restrict__ psum){
  __shared__ int sh[256];
  int base = blockIdx.x*1024 + threadIdx.x*4;
  int s = 0;
  #pragma unroll
  for(int j=0;j<4;j++){ int i=base+j; if(i<NN) s += deg[i]; }
  sh[threadIdx.x]=s; __syncthreads();
  for(int st=128; st>0; st>>=1){ if(threadIdx.x<st) sh[threadIdx.x]+=sh[threadIdx.x+st]; __syncthreads(); }
  if(threadIdx.x==0) psum[blockIdx.x]=sh[0];
}

// block 0: serial scan of psum; blocks 1..4: fold-in the attention-weight precompute (k_prew)
__global__ void k_scan2_prew(int* __restrict__ psum, int nb,
                             const float* __restrict__ We, const float* __restrict__ al,
                             const float* __restrict__ ar, float* __restrict__ w_elr){
  if(blockIdx.x == 0){
    if(threadIdx.x==0){ int acc=0; for(int i=0;i<nb;i++){ int v=psum[i]; psum[i]=acc; acc+=v; } psum[nb]=acc; }
    return;
  }
  int t = (blockIdx.x-1)*256 + threadIdx.x;   // 0..1023
  int layer = t>>9, o = (t>>6)&7, k = t&63;
  const float* a = (o<4 ? al : ar) + layer*256 + (o&3)*64;
  const float* w = We + k*64;
  float s = 0.f;
  for(int d2=0; d2<64; ++d2) s += w[d2]*a[d2];
  w_elr[t] = s;
}

__global__ void k_scan3(const int* __restrict__ deg, const int* __restrict__ psum, int* __restrict__ rowp){
  __shared__ int sh[256];
  int t = threadIdx.x;
  int base = blockIdx.x*1024 + t*4;
  int v[4]; int s=0;
  #pragma unroll
  for(int j=0;j<4;j++){ int i=base+j; v[j] = (i<NN)?deg[i]:0; s+=v[j]; }
  sh[t]=s; __syncthreads();
  for(int st=1; st<256; st<<=1){
    int add = (t>=st)? sh[t-st] : 0;
    __syncthreads();
    sh[t] += add;
    __syncthreads();
  }
  int excl = sh[t]-s + psum[blockIdx.x];
  #pragma unroll
  for(int j=0;j<4;j++){ int i=base+j; if(i<NN){ rowp[i]=excl; excl+=v[j]; } }
  if(blockIdx.x==0 && t==0) rowp[NN] = psum[NB_SCAN];
}

__global__ void k_fill(const int* __restrict__ src, const int* __restrict__ dst,
                       const int* __restrict__ rowp, int* __restrict__ cnt, int* __restrict__ csrc){
  int e = blockIdx.x*256 + threadIdx.x;
  if(e < EE){
    int d = dst[e];
    int p = atomicAdd(&cnt[d], 1);
    csrc[rowp[d] + p] = src[e];
  }
}

// ---------------- GEMM tile machinery (64x64 C-tile, 256 thr, 4x4/thr) ----------------
// As: ROW-MAJOR [64 rows][stride 68] (odd chunk-stride 17 => conflict-free f4 writes,
//     2-way scalar broadcast reads). Bs: [k][col], staged contiguously per instruction.
__device__ __forceinline__ void load_A_tile(const float* __restrict__ A, int row0, int lda, int kcol0, float* As){
  int t = threadIdx.x;
  int lr = t>>2;             // row 0..63
  int lc = (t&3)*16;         // col chunk base
  float4 a0,a1,a2,a3;
  int row = row0 + lr;
  if(row < NN){
    const float* ap = A + (size_t)row*lda + kcol0 + lc;
    a0=*(const float4*)ap; a1=*(const float4*)(ap+4); a2=*(const float4*)(ap+8); a3=*(const float4*)(ap+12);
  } else {
    a0=a1=a2=a3=make_float4(0.f,0.f,0.f,0.f);
  }
  float* d = As + lr*68 + lc;
  *(float4*)(d)    = a0;
  *(float4*)(d+4)  = a1;
  *(float4*)(d+8)  = a2;
  *(float4*)(d+12) = a3;
}

__device__ __forceinline__ void load_B_tile(const float* __restrict__ B, int krow0, float* Bs){
  int t = threadIdx.x;
  int r  = t>>4;             // 0..15
  int c4 = (t&15)*4;
  #pragma unroll
  for(int m=0;m<4;m++){
    int row = m*16 + r;
    *(float4*)(Bs + row*64 + c4) = *(const float4*)(B + (size_t)(krow0+row)*64 + c4);
  }
}

__device__ __forceinline__ void tile64_compute(const float* __restrict__ As, const float* __restrict__ Bs,
                                               float acc[4][4], int ty, int tx){
  #pragma unroll 4
  for(int kk=0; kk<64; kk++){
    float a0 = As[(ty*4+0)*68 + kk];
    float a1 = As[(ty*4+1)*68 + kk];
    float a2 = As[(ty*4+2)*68 + kk];
    float a3 = As[(ty*4+3)*68 + kk];
    float4 b = *(const float4*)(Bs + kk*64 + tx*4);
    acc[0][0]+=a0*b.x; acc[0][1]+=a0*b.y; acc[0][2]+=a0*b.z; acc[0][3]+=a0*b.w;
    acc[1][0]+=a1*b.x; acc[1][1]+=a1*b.y; acc[1][2]+=a1*b.z; acc[1][3]+=a1*b.w;
    acc[2][0]+=a2*b.x; acc[2][1]+=a2*b.y; acc[2][2]+=a2*b.z; acc[2][3]+=a2*b.w;
    acc[3][0]+=a3*b.x; acc[3][1]+=a3*b.y; acc[3][2]+=a3*b.z; acc[3][3]+=a3*b.w;
  }
}

// proj_feat = ft @ Wp   [NN,512]@[512,64]
__global__ __launch_bounds__(256, 4) void k_gemm_proj(const float* __restrict__ A, const float* __restrict__ B, float* __restrict__ C){
  __shared__ float As[64*68];
  __shared__ float Bs[64*64];
  int row0 = blockIdx.x*64;
  int ty = threadIdx.x>>4, tx = threadIdx.x&15;
  float acc[4][4] = {};
  #pragma unroll 1
  for(int kt=0; kt<IND; kt+=64){
    __syncthreads();
    load_A_tile(A, row0, IND, kt, As);
    load_B_tile(B, kt, Bs);
    __syncthreads();
    tile64_compute(As, Bs, acc, ty, tx);
  }
  #pragma unroll
  for(int i=0;i<4;i++){
    int row = row0 + ty*4 + i;
    if(row < NN) *(float4*)(C + (size_t)row*64 + tx*4) = make_float4(acc[i][0],acc[i][1],acc[i][2],acc[i][3]);
  }
}

// pooled = cur@Wg; pack {cur,pooled} as half2; and fused el/er (folded-weight dots)
__global__ __launch_bounds__(256, 4) void k_packeler(const float* __restrict__ cur, const float* __restrict__ Wg,
                                                     const float* __restrict__ welr, __half2* __restrict__ pack,
                                                     float* __restrict__ el, float* __restrict__ er){
  __shared__ float As[64*68];
  __shared__ float Bs[64*64];
  __shared__ float Ws[512];
  int t = threadIdx.x;
  int row0 = blockIdx.x*64;
  int ty = t>>4, tx = t&15;
  load_A_tile(cur, row0, 64, 0, As);
  load_B_tile(Wg, 0, Bs);
  if(t < 128) *(float4*)(Ws + t*4) = *(const float4*)(welr + t*4);
  __syncthreads();
  float acc[4][4] = {};
  tile64_compute(As, Bs, acc, ty, tx);
  float po[8][4];
  #pragma unroll
  for(int o=0;o<8;o++)
    #pragma unroll
    for(int i=0;i<4;i++) po[o][i] = 0.f;
  #pragma unroll
  for(int i=0;i<4;i++){
    int row = row0 + ty*4 + i;
    float4 cv = make_float4(0.f,0.f,0.f,0.f);
    if(row < NN) cv = *(const float4*)(cur + (size_t)row*64 + tx*4);
    union { uint4 u; __half2 h[4]; } pk;
    pk.h[0] = __floats2half2_rn(cv.x, acc[i][0]);
    pk.h[1] = __floats2half2_rn(cv.y, acc[i][1]);
    pk.h[2] = __floats2half2_rn(cv.z, acc[i][2]);
    pk.h[3] = __floats2half2_rn(cv.w, acc[i][3]);
    if(row < NN) *(uint4*)(pack + (size_t)row*64 + tx*4) = pk.u;
    #pragma unroll
    for(int o=0;o<8;o++){
      float4 w = *(const float4*)(Ws + o*64 + tx*4);
      po[o][i] += cv.x*w.x + cv.y*w.y + cv.z*w.z + cv.w*w.w;
    }
  }
  #pragma unroll
  for(int st=1; st<16; st<<=1)
    #pragma unroll
    for(int o=0;o<8;o++)
      #pragma unroll
      for(int i=0;i<4;i++)
        po[o][i] += __shfl_xor(po[o][i], st, 64);
  if(tx < 8){
    #pragma unroll
    for(int i=0;i<4;i++){
      int row = row0 + ty*4 + i;
      if(row < NN){
        if(tx < 4) el[(size_t)row*4 + tx]     = po[tx][i];
        else       er[(size_t)row*4 + tx - 4] = po[tx][i];
      }
    }
  }
}

// per-node edge kernel: lane-parallel exp -> LDS, then uniform j-loop gathers one half2 stream
__global__ __launch_bounds__(256) void k_edge(const int* __restrict__ rowp, const int* __restrict__ csrc,
    const float* __restrict__ el, const float* __restrict__ er, const float* __restrict__ cur,
    const __half2* __restrict__ pack,
    const float* __restrict__ Wg, const float* __restrict__ bg, float* __restrict__ aggcg)
{
  __shared__ int    ssh[4][64];
  __shared__ float4 xsh[4][64];
  int wid = threadIdx.x>>6, lane = threadIdx.x&63;
  int d = blockIdx.x*4 + wid;
  if(d >= NN) return;
  int e0 = rowp[d], e1 = rowp[d+1];
  float4 erd = *(const float4*)(er + (size_t)d*4);
  float n0=0,n1=0,n2=0,n3=0, den0=0,den1=0,den2=0,den3=0, mn=0, mxp=-1e30f;

  for(int c=e0; c<e1; c+=64){
    int jmax = min(64, e1-c);
    float x0=0.f, x1=0.f, x2=0.f, x3=0.f; int s=0;
    if(lane < jmax){
      s = csrc[c+lane];
      float4 ev = *(const float4*)(el + (size_t)s*4);
      x0 = __expf(lrelu(ev.x+erd.x, 0.2f));
      x1 = __expf(lrelu(ev.y+erd.y, 0.2f));
      x2 = __expf(lrelu(ev.z+erd.z, 0.2f));
      x3 = __expf(lrelu(ev.w+erd.w, 0.2f));
      den0+=x0; den1+=x1; den2+=x2; den3+=x3;
    }
    ssh[wid][lane] = s;
    xsh[wid][lane] = make_float4(x0,x1,x2,x3);
    for(int j=0; j<jmax; ++j){
      int sj = __builtin_amdgcn_readfirstlane(ssh[wid][j]);
      float4 xj = xsh[wid][j];
      float2 f = __half22float2(pack[(size_t)sj*64 + lane]);   // {cur, pooled}
      n0 += xj.x*f.x; n1 += xj.y*f.x; n2 += xj.z*f.x; n3 += xj.w*f.x;
      mn += f.x;
      mxp = fmaxf(mxp, f.y);
    }
  }
  #pragma unroll
  for(int st=32; st; st>>=1){
    den0+=__shfl_xor(den0,st,64); den1+=__shfl_xor(den1,st,64);
    den2+=__shfl_xor(den2,st,64); den3+=__shfl_xor(den3,st,64);
  }
  float cd  = cur[(size_t)d*64 + lane];
  float mnn = mn / (float)(e1-e0);
  float4 w0 = *(const float4*)(Wg + lane*4);
  float4 w1 = *(const float4*)(Wg + (64+lane)*4);
  float4 w2 = *(const float4*)(Wg + (128+lane)*4);
  float g0 = cd*w0.x + mxp*w1.x + mnn*w2.x;
  float g1 = cd*w0.y + mxp*w1.y + mnn*w2.y;
  float g2 = cd*w0.z + mxp*w1.z + mnn*w2.z;
  float g3 = cd*w0.w + mxp*w1.w + mnn*w2.w;
  #pragma unroll
  for(int st=32; st; st>>=1){
    g0+=__shfl_xor(g0,st,64); g1+=__shfl_xor(g1,st,64);
    g2+=__shfl_xor(g2,st,64); g3+=__shfl_xor(g3,st,64);
  }
  g0 = 1.f/(1.f+__expf(-(g0+bg[0])));
  g1 = 1.f/(1.f+__expf(-(g1+bg[1])));
  g2 = 1.f/(1.f+__expf(-(g2+bg[2])));
  g3 = 1.f/(1.f+__expf(-(g3+bg[3])));
  float* od = aggcg + (size_t)d*256;
  od[lane]       = g0 * n0/den0;
  od[64 + lane]  = g1 * n1/den1;
  od[128 + lane] = g2 * n2/den2;
  od[192 + lane] = g3 * n3/den3;
}

// layer0 post: cur1 = lrelu(0.25 * aggcg[N,256] @ WvStack[256,64])
__global__ __launch_bounds__(256, 4) void k_post0(const float* __restrict__ A, const float* __restrict__ B, float* __restrict__ C){
  __shared__ float As[64*68];
  __shared__ float Bs[64*64];
  int row0 = blockIdx.x*64;
  int ty = threadIdx.x>>4, tx = threadIdx.x&15;
  float acc[4][4] = {};
  #pragma unroll 1
  for(int kt=0; kt<256; kt+=64){
    __syncthreads();
    load_A_tile(A, row0, 256, kt, As);
    load_B_tile(B, kt, Bs);
    __syncthreads();
    tile64_compute(As, Bs, acc, ty, tx);
  }
  #pragma unroll
  for(int i=0;i<4;i++){
    int row = row0 + ty*4 + i;
    if(row < NN) *(float4*)(C + (size_t)row*64 + tx*4) =
      make_float4(lrelu(0.25f*acc[i][0],0.01f), lrelu(0.25f*acc[i][1],0.01f),
                  lrelu(0.25f*acc[i][2],0.01f), lrelu(0.25f*acc[i][3],0.01f));
  }
}

// fused layer1-post + final: out = [pf, lrelu(aggcg_h @ Wv1_h)_h] @ Wtran + btran
__global__ __launch_bounds__(256, 4) void k_final2(const float* __restrict__ pf, const float* __restrict__ aggcg,
                                                   const float* __restrict__ Wv1, const float* __restrict__ Wt,
                                                   const float* __restrict__ bt, float* __restrict__ C){
  __shared__ float As[64*68];
  __shared__ float Bs[64*64];
  int row0 = blockIdx.x*64;
  int ty = threadIdx.x>>4, tx = threadIdx.x&15;
  float accF[4][4] = {};
  load_A_tile(pf, row0, 64, 0, As);
  load_B_tile(Wt, 0, Bs);
  __syncthreads();
  tile64_compute(As, Bs, accF, ty, tx);
  #pragma unroll 1
  for(int h=0; h<4; ++h){
    __syncthreads();
    load_A_tile(aggcg + h*64, row0, 256, 0, As);
    load_B_tile(Wv1 + (size_t)h*4096, 0, Bs);
    __syncthreads();
    float acc1[4][4] = {};
    tile64_compute(As, Bs, acc1, ty, tx);
    __syncthreads();                           // all reads of As/Bs done
    #pragma unroll
    for(int i=0;i<4;i++){
      float4 v = make_float4(lrelu(acc1[i][0],0.01f), lrelu(acc1[i][1],0.01f),
                             lrelu(acc1[i][2],0.01f), lrelu(acc1[i][3],0.01f));
      *(float4*)(As + (ty*4+i)*68 + tx*4) = v;  // row-major, conflict-free
    }
    load_B_tile(Wt, 64 + h*64, Bs);
    __syncthreads();
    tile64_compute(As, Bs, accF, ty, tx);
  }
  float4 bias = *(const float4*)(bt + tx*4);
  #pragma unroll
  for(int i=0;i<4;i++){
    int row = row0 + ty*4 + i;
    if(row < NN){
      *(float4*)(C + (size_t)row*64 + tx*4) =
        make_float4(accF[i][0]+bias.x, accF[i][1]+bias.y, accF[i][2]+bias.z, accF[i][3]+bias.w);
    }
  }
}

extern "C" void kernel_launch(void* const* d_in, const int* in_sizes, int n_in,
                              void* d_out, int out_size, void* d_ws, size_t ws_size,
                              hipStream_t stream) {
  const float* ft    = (const float*)d_in[0];
  const float* Wp    = (const float*)d_in[1];
  const float* We    = (const float*)d_in[2];
  const float* a_l   = (const float*)d_in[3];
  const float* a_r   = (const float*)d_in[4];
  const float* Wv    = (const float*)d_in[5];
  const float* Wgp   = (const float*)d_in[6];
  const float* Wgate = (const float*)d_in[7];
  const float* bgate = (const float*)d_in[8];
  const float* Wtran = (const float*)d_in[9];
  const float* btran = (const float*)d_in[10];
  const int*   src   = (const int*)d_in[11];
  const int*   dst   = (const int*)d_in[12];
  float* out = (float*)d_out;

  char* p = (char*)d_ws;
  auto alloc = [&](size_t bytes)->char* { char* r = p; p += (bytes + 255) & ~(size_t)255; return r; };
  int* deg  = (int*)alloc((size_t)NN*4);      // deg & cnt adjacent: one memset covers both
  int* cnt  = (int*)alloc((size_t)NN*4);
  int* rowp = (int*)alloc((size_t)(NN+1)*4);
  int* psum = (int*)alloc(64*4);
  int* csrc = (int*)alloc((size_t)EE*4);
  float*   pf    = (float*)alloc((size_t)NN*64*4);
  float*   cur1  = (float*)alloc((size_t)NN*64*4);
  float*   elb   = (float*)alloc((size_t)NN*4*4);
  float*   erb   = (float*)alloc((size_t)NN*4*4);
  __half2* pack  = (__half2*)alloc((size_t)NN*64*4);
  float*   aggcg = (float*)alloc((size_t)NN*256*4);
  float*   welr  = (float*)alloc(1024*4);

  hipMemsetAsync(deg, 0, (size_t)((char*)cnt - (char*)deg) + (size_t)NN*4, stream);
  k_deg<<<(EE+255)/256, 256, 0, stream>>>(dst, deg);
  k_scan1<<<NB_SCAN, 256, 0, stream>>>(deg, psum);
  k_scan2_prew<<<5, 256, 0, stream>>>(psum, NB_SCAN, We, a_l, a_r, welr);
  k_scan3<<<NB_SCAN, 256, 0, stream>>>(deg, psum, rowp);
  k_fill<<<(EE+255)/256, 256, 0, stream>>>(src, dst, rowp, cnt, csrc);

  k_gemm_proj<<<(NN+63)/64, 256, 0, stream>>>(ft, Wp, pf);

  int gb = (NN+63)/64;
  // layer 0 (cur = pf)
  k_packeler<<<gb, 256, 0, stream>>>(pf, Wgp, welr, pack, elb, erb);
  k_edge<<<NN/4, 256, 0, stream>>>(rowp, csrc, elb, erb, pf, pack, Wgate, bgate, aggcg);
  k_post0<<<gb, 256, 0, stream>>>(aggcg, Wv, cur1);
  // layer 1 (cur = cur1)
  k_packeler<<<gb, 256, 0, stream>>>(cur1, Wgp + 4096, welr + 512, pack, elb, erb);
  k_edge<<<NN/4, 256, 0, stream>>>(rowp, csrc, elb, erb, cur1, pack, Wgate + 768, bgate + 4, aggcg);
  // fused layer1-post + final transform
  k_final2<<<gb, 256, 0, stream>>>(pf, aggcg, Wv + 16384, Wtran, btran, out);
}